// Round 1
// baseline (12469.604 us; speedup 1.0000x reference)
//
#include <hip/hip_runtime.h>
#include <hip/hip_bf16.h>
#include <math.h>

#define N1 60000
#define N2 50000
#define DIM 128
#define NREL 16
#define NB 4
#define LCOM 100

// ---------------- concept layer (g1): scatter-mean ----------------
__global__ void k_concept_scatter(const int* __restrict__ ei, const float* __restrict__ x,
                                  float* __restrict__ agg, float* __restrict__ deg, int E) {
    int gid = blockIdx.x * blockDim.x + threadIdx.x;
    int e = gid >> 5, lane = gid & 31;
    if (e >= E) return;
    int src = ei[e], dst = ei[E + e];
    const float4 v = *(const float4*)(x + (long long)src * DIM + lane * 4);
    float* a = agg + (long long)dst * DIM + lane * 4;
    atomicAdd(a + 0, v.x); atomicAdd(a + 1, v.y);
    atomicAdd(a + 2, v.z); atomicAdd(a + 3, v.w);
    if (lane == 0) atomicAdd(deg + dst, 1.0f);
}

__global__ void k_concept_final(const float* __restrict__ emb, const float* __restrict__ agg,
                                const float* __restrict__ deg, float* __restrict__ xg1) {
    int i = blockIdx.x * blockDim.x + threadIdx.x;
    if (i >= N1 * DIM) return;
    int row = i >> 7;
    float v = emb[i] + agg[i] / fmaxf(deg[row], 1.0f);
    xg1[i] = fmaxf(v, 0.0f);
}

// tyw_t[d*100 + l] = x_g1[lc[l], d] * w[d]   (transposed for LDS use later)
__global__ void k_tyw(const float* __restrict__ xg1, const int* __restrict__ lc,
                      const float* __restrict__ w, float* __restrict__ tyw_t) {
    int tid = blockIdx.x * blockDim.x + threadIdx.x;
    if (tid >= LCOM * DIM) return;
    int d = tid / LCOM, l = tid % LCOM;
    tyw_t[tid] = xg1[(long long)lc[l] * DIM + d] * w[d];
}

// ---------------- rgcn: per-(dst,etype) counts ----------------
__global__ void k_cnt(const int* __restrict__ ei, const int* __restrict__ et,
                      float* __restrict__ cnt, int E) {
    int e = blockIdx.x * blockDim.x + threadIdx.x;
    if (e >= E) return;
    atomicAdd(cnt + ei[E + e] * NREL + et[e], 1.0f);
}

// agg[dst, b, :] += comp[t,b]/max(cnt,1) * x[src, :]
__global__ void k_rgcn_scatter(const int* __restrict__ ei, const int* __restrict__ et,
                               const float* __restrict__ cnt, const float* __restrict__ comp,
                               const float* __restrict__ x, float* __restrict__ agg, int E) {
    int gid = blockIdx.x * blockDim.x + threadIdx.x;
    int e = gid >> 5, lane = gid & 31;
    if (e >= E) return;
    int src = ei[e], dst = ei[E + e], t = et[e];
    float nrm = 1.0f / fmaxf(cnt[dst * NREL + t], 1.0f);
    const float4 v = *(const float4*)(x + (long long)src * DIM + lane * 4);
    float* ag = agg + (long long)dst * (NB * DIM) + lane * 4;
#pragma unroll
    for (int b = 0; b < NB; b++) {
        float c = comp[t * NB + b] * nrm;
        float* p = ag + b * DIM;
        atomicAdd(p + 0, c * v.x); atomicAdd(p + 1, c * v.y);
        atomicAdd(p + 2, c * v.z); atomicAdd(p + 3, c * v.w);
    }
}

// ---------------- GEMM: out(M,128) = x(M,128)@root + agg(M,512)@basis_flat + bias ----------------
// Block 128x128 tile, 256 threads, each 8x8 outputs. K = 640 in BK=16 steps.
__global__ __launch_bounds__(256) void k_gemm(const float* __restrict__ x, const float* __restrict__ agg,
                                              const float* __restrict__ root, const float* __restrict__ basis,
                                              const float* __restrict__ bias, float* __restrict__ out,
                                              int relu) {
    __shared__ __align__(16) float As[128][17];
    __shared__ __align__(16) float Bs[16][128];
    int tid = threadIdx.x;
    int tx = tid & 15, ty = tid >> 4;
    int row0 = blockIdx.x * 128;
    float acc[8][8] = {};
    for (int k0 = 0; k0 < 640; k0 += 16) {
        // stage B tile (16x128): W[k][n] = k<128 ? root : basis_flat
        {
            const float* Bsrc = (k0 < 128) ? (root + k0 * 128) : (basis + (k0 - 128) * 128);
            int idx = tid * 8;
            int kk = idx >> 7, col = idx & 127;
            float4 b0 = *(const float4*)(Bsrc + kk * 128 + col);
            float4 b1 = *(const float4*)(Bsrc + kk * 128 + col + 4);
            *(float4*)(&Bs[kk][col]) = b0;
            *(float4*)(&Bs[kk][col + 4]) = b1;
        }
        // stage A tile (128x16): rows row0..row0+127, cols k0..k0+15
        {
            int idx = tid * 8;
            int r = idx >> 4, kq = idx & 15;  // kq in {0,8}
            int rg = row0 + r;
            float4 a0 = {0, 0, 0, 0}, a1 = {0, 0, 0, 0};
            if (rg < N2) {
                const float* Asrc = (k0 < 128) ? (x + (long long)rg * 128 + k0)
                                               : (agg + (long long)rg * 512 + (k0 - 128));
                a0 = *(const float4*)(Asrc + kq);
                a1 = *(const float4*)(Asrc + kq + 4);
            }
            As[r][kq + 0] = a0.x; As[r][kq + 1] = a0.y; As[r][kq + 2] = a0.z; As[r][kq + 3] = a0.w;
            As[r][kq + 4] = a1.x; As[r][kq + 5] = a1.y; As[r][kq + 6] = a1.z; As[r][kq + 7] = a1.w;
        }
        __syncthreads();
#pragma unroll
        for (int kk = 0; kk < 16; kk++) {
            float4 b0 = *(const float4*)(&Bs[kk][tx * 4]);
            float4 b1 = *(const float4*)(&Bs[kk][64 + tx * 4]);
#pragma unroll
            for (int i = 0; i < 8; i++) {
                float a = As[ty * 8 + i][kk];
                acc[i][0] = fmaf(a, b0.x, acc[i][0]);
                acc[i][1] = fmaf(a, b0.y, acc[i][1]);
                acc[i][2] = fmaf(a, b0.z, acc[i][2]);
                acc[i][3] = fmaf(a, b0.w, acc[i][3]);
                acc[i][4] = fmaf(a, b1.x, acc[i][4]);
                acc[i][5] = fmaf(a, b1.y, acc[i][5]);
                acc[i][6] = fmaf(a, b1.z, acc[i][6]);
                acc[i][7] = fmaf(a, b1.w, acc[i][7]);
            }
        }
        __syncthreads();
    }
    int c0 = tx * 4, c1 = 64 + tx * 4;
    float4 bv0 = *(const float4*)(bias + c0);
    float4 bv1 = *(const float4*)(bias + c1);
#pragma unroll
    for (int i = 0; i < 8; i++) {
        int rg = row0 + ty * 8 + i;
        if (rg >= N2) continue;
        float4 o0 = {acc[i][0] + bv0.x, acc[i][1] + bv0.y, acc[i][2] + bv0.z, acc[i][3] + bv0.w};
        float4 o1 = {acc[i][4] + bv1.x, acc[i][5] + bv1.y, acc[i][6] + bv1.z, acc[i][7] + bv1.w};
        if (relu) {
            o0.x = fmaxf(o0.x, 0.f); o0.y = fmaxf(o0.y, 0.f); o0.z = fmaxf(o0.z, 0.f); o0.w = fmaxf(o0.w, 0.f);
            o1.x = fmaxf(o1.x, 0.f); o1.y = fmaxf(o1.y, 0.f); o1.z = fmaxf(o1.z, 0.f); o1.w = fmaxf(o1.w, 0.f);
        }
        *(float4*)(out + (long long)rg * 128 + c0) = o0;
        *(float4*)(out + (long long)rg * 128 + c1) = o1;
    }
}

// ---------------- logits + softmax: one wave per row ----------------
__global__ __launch_bounds__(256) void k_logits(const float* __restrict__ h2,
                                                const float* __restrict__ tyw_t,
                                                float* __restrict__ out, int M) {
    __shared__ __align__(16) float tyl[DIM * LCOM + 64];  // pad for lane>=36 dummy reads
    __shared__ __align__(16) float xs[16][DIM];
    int tid = threadIdx.x;
    for (int i = tid; i < DIM * LCOM; i += 256) tyl[i] = tyw_t[i];
    int base = blockIdx.x * 16;
    for (int i = tid; i < 16 * DIM; i += 256) {
        int r = i >> 7, d = i & 127;
        int rg = base + r;
        xs[r][d] = (rg < M) ? h2[(long long)rg * DIM + d] : 0.f;
    }
    __syncthreads();
    int wave = tid >> 6, lane = tid & 63;
#pragma unroll
    for (int rr = 0; rr < 4; rr++) {
        int r = wave * 4 + rr;
        int row = base + r;
        if (row >= M) continue;
        float acc0 = 0.f, acc1 = 0.f;
#pragma unroll 8
        for (int d = 0; d < DIM; d++) {
            float xv = xs[r][d];
            acc0 = fmaf(xv, tyl[d * LCOM + lane], acc0);
            acc1 = fmaf(xv, tyl[d * LCOM + 64 + lane], acc1);  // garbage for lane>=36, discarded
        }
        float m = fmaxf(acc0, (lane < 36) ? acc1 : -INFINITY);
        for (int off = 32; off; off >>= 1) m = fmaxf(m, __shfl_xor(m, off, 64));
        float e0 = __expf(acc0 - m);
        float e1 = (lane < 36) ? __expf(acc1 - m) : 0.f;
        float s = e0 + e1;
        for (int off = 32; off; off >>= 1) s += __shfl_xor(s, off, 64);
        float inv = 1.0f / s;
        out[(long long)row * LCOM + lane] = e0 * inv;
        if (lane < 36) out[(long long)row * LCOM + 64 + lane] = e1 * inv;
    }
}

extern "C" void kernel_launch(void* const* d_in, const int* in_sizes, int n_in,
                              void* d_out, int out_size, void* d_ws, size_t ws_size,
                              hipStream_t stream) {
    const int* ei2 = (const int*)d_in[0];
    const int* et2 = (const int*)d_in[1];
    const int* ei1 = (const int*)d_in[2];
    const int* lc = (const int*)d_in[3];
    const float* emb = (const float*)d_in[4];
    const float* basis1 = (const float*)d_in[5];
    const float* comp1 = (const float*)d_in[6];
    const float* root1 = (const float*)d_in[7];
    const float* bias1 = (const float*)d_in[8];
    const float* basis2 = (const float*)d_in[9];
    const float* comp2 = (const float*)d_in[10];
    const float* root2 = (const float*)d_in[11];
    const float* bias2 = (const float*)d_in[12];
    const float* wts = (const float*)d_in[13];
    float* out = (float*)d_out;
    int E2 = in_sizes[0] / 2, E1 = in_sizes[2] / 2;

    float* ws = (float*)d_ws;
    float* xg1 = ws;                   // 7,680,000 (doubles as concept agg)
    float* deg = xg1 + 7680000;        // 60,000
    float* cnt = deg + 60000;          // 800,000
    float* agg = cnt + 800000;         // 25,600,000
    float* h1 = agg + 25600000;        // 6,400,000
    float* h2 = h1 + 6400000;          // 6,400,000
    float* tyw = h2 + 6400000;         // 12,800

    // zero: concept agg (xg1 buf), deg, cnt
    hipMemsetAsync(xg1, 0, (size_t)(7680000 + 60000 + 800000) * 4, stream);

    // concept layer on g1
    k_concept_scatter<<<(E1 * 32 + 255) / 256, 256, 0, stream>>>(ei1, emb, xg1, deg, E1);
    k_concept_final<<<(N1 * DIM + 255) / 256, 256, 0, stream>>>(emb, xg1, deg, xg1);
    k_tyw<<<(LCOM * DIM + 255) / 256, 256, 0, stream>>>(xg1, lc, wts, tyw);

    // shared (dst,etype) counts for both rgcn layers
    k_cnt<<<(E2 + 255) / 256, 256, 0, stream>>>(ei2, et2, cnt, E2);

    // rgcn layer 1: x = xg1[:50000]
    hipMemsetAsync(agg, 0, (size_t)25600000 * 4, stream);
    k_rgcn_scatter<<<(E2 * 32 + 255) / 256, 256, 0, stream>>>(ei2, et2, cnt, comp1, xg1, agg, E2);
    k_gemm<<<(N2 + 127) / 128, 256, 0, stream>>>(xg1, agg, root1, basis1, bias1, h1, 1);

    // rgcn layer 2: input h1
    hipMemsetAsync(agg, 0, (size_t)25600000 * 4, stream);
    k_rgcn_scatter<<<(E2 * 32 + 255) / 256, 256, 0, stream>>>(ei2, et2, cnt, comp2, h1, agg, E2);
    k_gemm<<<(N2 + 127) / 128, 256, 0, stream>>>(h1, agg, root2, basis2, bias2, h2, 0);

    // logits + softmax
    k_logits<<<(N2 + 15) / 16, 256, 0, stream>>>(h2, tyw, out, N2);
}

// Round 2
// 1182.690 us; speedup vs baseline: 10.5434x; 10.5434x over previous
//
#include <hip/hip_runtime.h>
#include <hip/hip_bf16.h>
#include <math.h>

#define N1 60000
#define N2 50000
#define DIM 128
#define NREL 16
#define NB 4
#define LCOM 100

// ---------------- histogram: in-degree per dst ----------------
__global__ void k_hist_deg(const int* __restrict__ ei, int* __restrict__ deg, int E) {
    int e = blockIdx.x * blockDim.x + threadIdx.x;
    if (e >= E) return;
    atomicAdd(deg + ei[E + e], 1);
}

// histogram per (dst, rel)
__global__ void k_hist_dt(const int* __restrict__ ei, const int* __restrict__ et,
                          int* __restrict__ cnt, int E) {
    int e = blockIdx.x * blockDim.x + threadIdx.x;
    if (e >= E) return;
    atomicAdd(cnt + ei[E + e] * NREL + et[e], 1);
}

// per-dst degree from per-(dst,rel) counts
__global__ void k_deg_from_cnt(const int* __restrict__ cnt, int* __restrict__ deg, int n) {
    int i = blockIdx.x * blockDim.x + threadIdx.x;
    if (i >= n) return;
    int s = 0;
#pragma unroll
    for (int t = 0; t < NREL; t++) s += cnt[i * NREL + t];
    deg[i] = s;
}

// ---------------- single-block exclusive scan (n <= ~1M) ----------------
__global__ __launch_bounds__(1024) void k_scan(const int* __restrict__ in, int* __restrict__ off,
                                               int* __restrict__ cur, int n) {
    __shared__ int sums[1024];
    int tid = threadIdx.x;
    int chunk = (n + 1023) >> 10;
    int lo = tid * chunk, hi = min(lo + chunk, n);
    int s = 0;
    for (int i = lo; i < hi; i++) s += in[i];
    sums[tid] = s;
    __syncthreads();
    for (int d = 1; d < 1024; d <<= 1) {
        int t = (tid >= d) ? sums[tid - d] : 0;
        __syncthreads();
        sums[tid] += t;
        __syncthreads();
    }
    int run = sums[tid] - s;  // exclusive prefix of this thread's chunk
    for (int i = lo; i < hi; i++) {
        off[i] = run; cur[i] = run;
        run += in[i];
    }
    if (tid == 1023) off[n] = sums[1023];
}

// scatter edges into CSR order: elist[pos] = src  (g1)
__global__ void k_csr_scatter1(const int* __restrict__ ei, int* __restrict__ cur,
                               int* __restrict__ elist, int E) {
    int e = blockIdx.x * blockDim.x + threadIdx.x;
    if (e >= E) return;
    int pos = atomicAdd(cur + ei[E + e], 1);
    elist[pos] = ei[e];
}

// scatter edges into CSR order: elist[pos] = (src<<4)|type  (g2; src<50000<2^16)
__global__ void k_csr_scatter2(const int* __restrict__ ei, const int* __restrict__ et,
                               int* __restrict__ cur, int* __restrict__ elist, int E) {
    int e = blockIdx.x * blockDim.x + threadIdx.x;
    if (e >= E) return;
    int pos = atomicAdd(cur + ei[E + e], 1);
    elist[pos] = (ei[e] << 4) | et[e];
}

// ---------------- concept layer: gather-mean, one wave per node ----------------
__global__ __launch_bounds__(256) void k_concept_gather(const float* __restrict__ emb,
                                                        const int* __restrict__ off,
                                                        const int* __restrict__ elist,
                                                        float* __restrict__ xg1, int n) {
    int node = blockIdx.x * 4 + (threadIdx.x >> 6);
    int lane = threadIdx.x & 63;
    if (node >= n) return;
    int s0 = off[node], s1 = off[node + 1];
    float2 acc = {0.f, 0.f};
    for (int i = s0; i < s1; i++) {
        int s = elist[i];
        float2 v = *(const float2*)(emb + (size_t)s * DIM + lane * 2);
        acc.x += v.x; acc.y += v.y;
    }
    float inv = 1.0f / (float)max(s1 - s0, 1);
    float2 e = *(const float2*)(emb + (size_t)node * DIM + lane * 2);
    float2 o = {fmaxf(e.x + acc.x * inv, 0.f), fmaxf(e.y + acc.y * inv, 0.f)};
    *(float2*)(xg1 + (size_t)node * DIM + lane * 2) = o;
}

// tyw_t[d*100 + l] = x_g1[lc[l], d] * w[d]
__global__ void k_tyw(const float* __restrict__ xg1, const int* __restrict__ lc,
                      const float* __restrict__ w, float* __restrict__ tyw_t) {
    int tid = blockIdx.x * blockDim.x + threadIdx.x;
    if (tid >= LCOM * DIM) return;
    int d = tid / LCOM, l = tid % LCOM;
    tyw_t[tid] = xg1[(size_t)lc[l] * DIM + d] * w[d];
}

// ---------------- rgcn aggregation: gather, one wave per dst ----------------
// agg[dst, b, :] = sum_e comp[t,b]/max(cnt[dst,t],1) * x[src]
__global__ __launch_bounds__(256) void k_rgcn_gather(const float* __restrict__ x,
                                                     const int* __restrict__ off,
                                                     const int* __restrict__ elist,
                                                     const int* __restrict__ cnt,
                                                     const float* __restrict__ comp,
                                                     float* __restrict__ agg, int n) {
    int node = blockIdx.x * 4 + (threadIdx.x >> 6);
    int lane = threadIdx.x & 63;
    if (node >= n) return;
    int s0 = off[node], s1 = off[node + 1];
    const int* cb = cnt + node * NREL;
    float2 a0 = {0.f, 0.f}, a1 = {0.f, 0.f}, a2 = {0.f, 0.f}, a3 = {0.f, 0.f};
    for (int i = s0; i < s1; i++) {
        int p = elist[i];
        int s = p >> 4, t = p & 15;
        float nrm = 1.0f / fmaxf((float)cb[t], 1.0f);
        float2 v = *(const float2*)(x + (size_t)s * DIM + lane * 2);
        float c0 = comp[t * NB + 0] * nrm;
        float c1 = comp[t * NB + 1] * nrm;
        float c2 = comp[t * NB + 2] * nrm;
        float c3 = comp[t * NB + 3] * nrm;
        a0.x = fmaf(c0, v.x, a0.x); a0.y = fmaf(c0, v.y, a0.y);
        a1.x = fmaf(c1, v.x, a1.x); a1.y = fmaf(c1, v.y, a1.y);
        a2.x = fmaf(c2, v.x, a2.x); a2.y = fmaf(c2, v.y, a2.y);
        a3.x = fmaf(c3, v.x, a3.x); a3.y = fmaf(c3, v.y, a3.y);
    }
    float* o = agg + (size_t)node * (NB * DIM) + lane * 2;
    *(float2*)(o + 0 * DIM) = a0;
    *(float2*)(o + 1 * DIM) = a1;
    *(float2*)(o + 2 * DIM) = a2;
    *(float2*)(o + 3 * DIM) = a3;
}

// ---------------- GEMM: out(M,128) = x(M,128)@root + agg(M,512)@basis_flat + bias ----------------
__global__ __launch_bounds__(256) void k_gemm(const float* __restrict__ x, const float* __restrict__ agg,
                                              const float* __restrict__ root, const float* __restrict__ basis,
                                              const float* __restrict__ bias, float* __restrict__ out,
                                              int relu) {
    __shared__ __align__(16) float As[128][17];
    __shared__ __align__(16) float Bs[16][128];
    int tid = threadIdx.x;
    int tx = tid & 15, ty = tid >> 4;
    int row0 = blockIdx.x * 128;
    float acc[8][8] = {};
    for (int k0 = 0; k0 < 640; k0 += 16) {
        {
            const float* Bsrc = (k0 < 128) ? (root + k0 * 128) : (basis + (k0 - 128) * 128);
            int idx = tid * 8;
            int kk = idx >> 7, col = idx & 127;
            float4 b0 = *(const float4*)(Bsrc + kk * 128 + col);
            float4 b1 = *(const float4*)(Bsrc + kk * 128 + col + 4);
            *(float4*)(&Bs[kk][col]) = b0;
            *(float4*)(&Bs[kk][col + 4]) = b1;
        }
        {
            int idx = tid * 8;
            int r = idx >> 4, kq = idx & 15;
            int rg = row0 + r;
            float4 a0 = {0, 0, 0, 0}, a1 = {0, 0, 0, 0};
            if (rg < N2) {
                const float* Asrc = (k0 < 128) ? (x + (size_t)rg * 128 + k0)
                                               : (agg + (size_t)rg * 512 + (k0 - 128));
                a0 = *(const float4*)(Asrc + kq);
                a1 = *(const float4*)(Asrc + kq + 4);
            }
            As[r][kq + 0] = a0.x; As[r][kq + 1] = a0.y; As[r][kq + 2] = a0.z; As[r][kq + 3] = a0.w;
            As[r][kq + 4] = a1.x; As[r][kq + 5] = a1.y; As[r][kq + 6] = a1.z; As[r][kq + 7] = a1.w;
        }
        __syncthreads();
#pragma unroll
        for (int kk = 0; kk < 16; kk++) {
            float4 b0 = *(const float4*)(&Bs[kk][tx * 4]);
            float4 b1 = *(const float4*)(&Bs[kk][64 + tx * 4]);
#pragma unroll
            for (int i = 0; i < 8; i++) {
                float a = As[ty * 8 + i][kk];
                acc[i][0] = fmaf(a, b0.x, acc[i][0]);
                acc[i][1] = fmaf(a, b0.y, acc[i][1]);
                acc[i][2] = fmaf(a, b0.z, acc[i][2]);
                acc[i][3] = fmaf(a, b0.w, acc[i][3]);
                acc[i][4] = fmaf(a, b1.x, acc[i][4]);
                acc[i][5] = fmaf(a, b1.y, acc[i][5]);
                acc[i][6] = fmaf(a, b1.z, acc[i][6]);
                acc[i][7] = fmaf(a, b1.w, acc[i][7]);
            }
        }
        __syncthreads();
    }
    int c0 = tx * 4, c1 = 64 + tx * 4;
    float4 bv0 = *(const float4*)(bias + c0);
    float4 bv1 = *(const float4*)(bias + c1);
#pragma unroll
    for (int i = 0; i < 8; i++) {
        int rg = row0 + ty * 8 + i;
        if (rg >= N2) continue;
        float4 o0 = {acc[i][0] + bv0.x, acc[i][1] + bv0.y, acc[i][2] + bv0.z, acc[i][3] + bv0.w};
        float4 o1 = {acc[i][4] + bv1.x, acc[i][5] + bv1.y, acc[i][6] + bv1.z, acc[i][7] + bv1.w};
        if (relu) {
            o0.x = fmaxf(o0.x, 0.f); o0.y = fmaxf(o0.y, 0.f); o0.z = fmaxf(o0.z, 0.f); o0.w = fmaxf(o0.w, 0.f);
            o1.x = fmaxf(o1.x, 0.f); o1.y = fmaxf(o1.y, 0.f); o1.z = fmaxf(o1.z, 0.f); o1.w = fmaxf(o1.w, 0.f);
        }
        *(float4*)(out + (size_t)rg * 128 + c0) = o0;
        *(float4*)(out + (size_t)rg * 128 + c1) = o1;
    }
}

// ---------------- logits + softmax: one wave per row ----------------
__global__ __launch_bounds__(256) void k_logits(const float* __restrict__ h2,
                                                const float* __restrict__ tyw_t,
                                                float* __restrict__ out, int M) {
    __shared__ __align__(16) float tyl[DIM * LCOM + 64];
    __shared__ __align__(16) float xs[16][DIM];
    int tid = threadIdx.x;
    for (int i = tid; i < DIM * LCOM; i += 256) tyl[i] = tyw_t[i];
    int base = blockIdx.x * 16;
    for (int i = tid; i < 16 * DIM; i += 256) {
        int r = i >> 7, d = i & 127;
        int rg = base + r;
        xs[r][d] = (rg < M) ? h2[(size_t)rg * DIM + d] : 0.f;
    }
    __syncthreads();
    int wave = tid >> 6, lane = tid & 63;
#pragma unroll
    for (int rr = 0; rr < 4; rr++) {
        int r = wave * 4 + rr;
        int row = base + r;
        if (row >= M) continue;
        float acc0 = 0.f, acc1 = 0.f;
#pragma unroll 8
        for (int d = 0; d < DIM; d++) {
            float xv = xs[r][d];
            acc0 = fmaf(xv, tyl[d * LCOM + lane], acc0);
            acc1 = fmaf(xv, tyl[d * LCOM + 64 + lane], acc1);
        }
        float m = fmaxf(acc0, (lane < 36) ? acc1 : -INFINITY);
        for (int off = 32; off; off >>= 1) m = fmaxf(m, __shfl_xor(m, off, 64));
        float e0 = __expf(acc0 - m);
        float e1 = (lane < 36) ? __expf(acc1 - m) : 0.f;
        float s = e0 + e1;
        for (int off = 32; off; off >>= 1) s += __shfl_xor(s, off, 64);
        float inv = 1.0f / s;
        out[(size_t)row * LCOM + lane] = e0 * inv;
        if (lane < 36) out[(size_t)row * LCOM + 64 + lane] = e1 * inv;
    }
}

extern "C" void kernel_launch(void* const* d_in, const int* in_sizes, int n_in,
                              void* d_out, int out_size, void* d_ws, size_t ws_size,
                              hipStream_t stream) {
    const int* ei2 = (const int*)d_in[0];
    const int* et2 = (const int*)d_in[1];
    const int* ei1 = (const int*)d_in[2];
    const int* lc = (const int*)d_in[3];
    const float* emb = (const float*)d_in[4];
    const float* basis1 = (const float*)d_in[5];
    const float* comp1 = (const float*)d_in[6];
    const float* root1 = (const float*)d_in[7];
    const float* bias1 = (const float*)d_in[8];
    const float* basis2 = (const float*)d_in[9];
    const float* comp2 = (const float*)d_in[10];
    const float* root2 = (const float*)d_in[11];
    const float* bias2 = (const float*)d_in[12];
    const float* wts = (const float*)d_in[13];
    float* out = (float*)d_out;
    int E2 = in_sizes[0] / 2, E1 = in_sizes[2] / 2;

    float* ws = (float*)d_ws;
    float* xg1 = ws;                     // 7,680,000 floats (later reused as h2)
    float* h1 = xg1 + 7680000;           // 6,400,000
    float* agg = h1 + 6400000;           // 25,600,000
    float* tyw = agg + 25600000;         // 12,800
    int* ipool = (int*)(tyw + 12800);
    // g1 CSR
    int* deg1 = ipool;                   // 60,000
    int* off1 = deg1 + 60000;            // 60,001
    int* cur1 = off1 + 60001;            // 60,000
    int* elist1 = cur1 + 60000;          // 800,000
    // g2 CSR (separate region; total ints ~2.73M = 10.9 MB)
    int* cnt2 = elist1 + 800000;         // 800,000  (per (dst,rel))
    int* deg2 = cnt2 + 800000;           // 50,000
    int* off2 = deg2 + 50000;            // 50,001
    int* cur2 = off2 + 50001;            // 50,000
    int* elist2 = cur2 + 50000;          // 800,000
    float* h2 = xg1;                     // alias: xg1 dead after gemm1/tyw

    // ---- g1 CSR + concept layer ----
    hipMemsetAsync(deg1, 0, 60000 * sizeof(int), stream);
    k_hist_deg<<<(E1 + 255) / 256, 256, 0, stream>>>(ei1, deg1, E1);
    k_scan<<<1, 1024, 0, stream>>>(deg1, off1, cur1, N1);
    k_csr_scatter1<<<(E1 + 255) / 256, 256, 0, stream>>>(ei1, cur1, elist1, E1);
    k_concept_gather<<<(N1 + 3) / 4, 256, 0, stream>>>(emb, off1, elist1, xg1, N1);
    k_tyw<<<(LCOM * DIM + 255) / 256, 256, 0, stream>>>(xg1, lc, wts, tyw);

    // ---- g2 CSR (shared by both rgcn layers) ----
    hipMemsetAsync(cnt2, 0, 800000 * sizeof(int), stream);
    k_hist_dt<<<(E2 + 255) / 256, 256, 0, stream>>>(ei2, et2, cnt2, E2);
    k_deg_from_cnt<<<(N2 + 255) / 256, 256, 0, stream>>>(cnt2, deg2, N2);
    k_scan<<<1, 1024, 0, stream>>>(deg2, off2, cur2, N2);
    k_csr_scatter2<<<(E2 + 255) / 256, 256, 0, stream>>>(ei2, et2, cur2, elist2, E2);

    // ---- rgcn layer 1 ----
    k_rgcn_gather<<<(N2 + 3) / 4, 256, 0, stream>>>(xg1, off2, elist2, cnt2, comp1, agg, N2);
    k_gemm<<<(N2 + 127) / 128, 256, 0, stream>>>(xg1, agg, root1, basis1, bias1, h1, 1);

    // ---- rgcn layer 2 ----
    k_rgcn_gather<<<(N2 + 3) / 4, 256, 0, stream>>>(h1, off2, elist2, cnt2, comp2, agg, N2);
    k_gemm<<<(N2 + 127) / 128, 256, 0, stream>>>(h1, agg, root2, basis2, bias2, h2, 0);

    // ---- logits + softmax ----
    k_logits<<<(N2 + 15) / 16, 256, 0, stream>>>(h2, tyw, out, N2);
}

// Round 4
// 1009.835 us; speedup vs baseline: 12.3482x; 1.1712x over previous
//
#include <hip/hip_runtime.h>
#include <hip/hip_bf16.h>
#include <math.h>

#define N1 60000
#define N2 50000
#define DIM 128
#define NREL 16
#define NB 4
#define LCOM 100

typedef __attribute__((ext_vector_type(8))) short short8;
typedef __attribute__((ext_vector_type(4))) float f32x4;

__device__ __forceinline__ float bf2f(unsigned short u) {
    union { unsigned int i; float f; } c; c.i = ((unsigned int)u) << 16; return c.f;
}
__device__ __forceinline__ unsigned short f2bf(float f) {
    union { float f; unsigned int i; } c; c.f = f;
    unsigned int r = c.i + 0x7FFF + ((c.i >> 16) & 1);  // RNE
    return (unsigned short)(r >> 16);
}
// split 8 floats into hi/lo bf16 (hi+lo accurate to ~2^-18 rel)
__device__ __forceinline__ void split8(float4 a, float4 b, short8& h, short8& l) {
    float f[8] = {a.x, a.y, a.z, a.w, b.x, b.y, b.z, b.w};
#pragma unroll
    for (int j = 0; j < 8; j++) {
        unsigned short hh = f2bf(f[j]);
        h[j] = (short)hh;
        l[j] = (short)f2bf(f[j] - bf2f(hh));
    }
}

// ---------------- weight prep: W=[root;basis_flat] (640x128) -> Wt_hi/lo[n*640+k] ----------------
__global__ void k_prep_w(const float* __restrict__ root, const float* __restrict__ basis,
                         unsigned short* __restrict__ Wh, unsigned short* __restrict__ Wl) {
    int t = blockIdx.x * blockDim.x + threadIdx.x;
    if (t >= 640 * 128) return;
    int k = t >> 7, n = t & 127;
    float v = (k < 128) ? root[k * 128 + n] : basis[(k - 128) * 128 + n];
    unsigned short h = f2bf(v);
    Wh[n * 640 + k] = h;
    Wl[n * 640 + k] = f2bf(v - bf2f(h));
}

// ---------------- histograms / CSR build ----------------
__global__ void k_hist_deg(const int* __restrict__ ei, int* __restrict__ deg, int E) {
    int e = blockIdx.x * blockDim.x + threadIdx.x;
    if (e >= E) return;
    atomicAdd(deg + ei[E + e], 1);
}

__global__ void k_hist_dt(const int* __restrict__ ei, const int* __restrict__ et,
                          int* __restrict__ cnt, int E) {
    int e = blockIdx.x * blockDim.x + threadIdx.x;
    if (e >= E) return;
    atomicAdd(cnt + ei[E + e] * NREL + et[e], 1);
}

__global__ void k_deg_from_cnt(const int* __restrict__ cnt, int* __restrict__ deg, int n) {
    int i = blockIdx.x * blockDim.x + threadIdx.x;
    if (i >= n) return;
    int s = 0;
#pragma unroll
    for (int t = 0; t < NREL; t++) s += cnt[i * NREL + t];
    deg[i] = s;
}

__global__ __launch_bounds__(1024) void k_scan(const int* __restrict__ in, int* __restrict__ off,
                                               int* __restrict__ cur, int n) {
    __shared__ int sums[1024];
    int tid = threadIdx.x;
    int chunk = (n + 1023) >> 10;
    int lo = tid * chunk, hi = min(lo + chunk, n);
    int s = 0;
    for (int i = lo; i < hi; i++) s += in[i];
    sums[tid] = s;
    __syncthreads();
    for (int d = 1; d < 1024; d <<= 1) {
        int t = (tid >= d) ? sums[tid - d] : 0;
        __syncthreads();
        sums[tid] += t;
        __syncthreads();
    }
    int run = sums[tid] - s;
    for (int i = lo; i < hi; i++) {
        off[i] = run; cur[i] = run;
        run += in[i];
    }
    if (tid == 1023) off[n] = sums[1023];
}

__global__ void k_csr_scatter1(const int* __restrict__ ei, int* __restrict__ cur,
                               int* __restrict__ elist, int E) {
    int e = blockIdx.x * blockDim.x + threadIdx.x;
    if (e >= E) return;
    int pos = atomicAdd(cur + ei[E + e], 1);
    elist[pos] = ei[e];
}

__global__ void k_csr_scatter2(const int* __restrict__ ei, const int* __restrict__ et,
                               int* __restrict__ cur, int* __restrict__ elist, int E) {
    int e = blockIdx.x * blockDim.x + threadIdx.x;
    if (e >= E) return;
    int pos = atomicAdd(cur + ei[E + e], 1);
    elist[pos] = (ei[e] << 4) | et[e];
}

// ---------------- concept layer: gather-mean (fp32), rows < n only ----------------
__global__ __launch_bounds__(256) void k_concept_gather(const float* __restrict__ emb,
                                                        const int* __restrict__ off,
                                                        const int* __restrict__ elist,
                                                        float* __restrict__ xg1, int n) {
    int node = blockIdx.x * 4 + (threadIdx.x >> 6);
    int lane = threadIdx.x & 63;
    if (node >= n) return;
    int s0 = off[node], s1 = off[node + 1];
    float2 acc = {0.f, 0.f};
    for (int i = s0; i < s1; i++) {
        int s = elist[i];
        float2 v = *(const float2*)(emb + (size_t)s * DIM + lane * 2);
        acc.x += v.x; acc.y += v.y;
    }
    float inv = 1.0f / (float)max(s1 - s0, 1);
    float2 e = *(const float2*)(emb + (size_t)node * DIM + lane * 2);
    float2 o = {fmaxf(e.x + acc.x * inv, 0.f), fmaxf(e.y + acc.y * inv, 0.f)};
    *(float2*)(xg1 + (size_t)node * DIM + lane * 2) = o;
}

// ---------------- tyw: compute concept row lc[l] on the fly, tyw_t[d*100+l] = relu(.)*w[d] ----------------
__global__ __launch_bounds__(64) void k_tyw(const float* __restrict__ emb,
                                            const int* __restrict__ off,
                                            const int* __restrict__ elist,
                                            const int* __restrict__ lc,
                                            const float* __restrict__ w,
                                            float* __restrict__ tyw_t) {
    int l = blockIdx.x;
    int lane = threadIdx.x;
    int row = lc[l];
    int s0 = off[row], s1 = off[row + 1];
    float2 acc = {0.f, 0.f};
    for (int i = s0; i < s1; i++) {
        int s = elist[i];
        float2 v = *(const float2*)(emb + (size_t)s * DIM + lane * 2);
        acc.x += v.x; acc.y += v.y;
    }
    float inv = 1.0f / (float)max(s1 - s0, 1);
    float2 e = *(const float2*)(emb + (size_t)row * DIM + lane * 2);
    int d0 = lane * 2;
    tyw_t[(size_t)d0 * LCOM + l] = fmaxf(e.x + acc.x * inv, 0.f) * w[d0];
    tyw_t[(size_t)(d0 + 1) * LCOM + l] = fmaxf(e.y + acc.y * inv, 0.f) * w[d0 + 1];
}

// ---------------- rgcn aggregation: gather (fp32) ----------------
__global__ __launch_bounds__(256) void k_rgcn_gather(const float* __restrict__ x,
                                                     const int* __restrict__ off,
                                                     const int* __restrict__ elist,
                                                     const int* __restrict__ cnt,
                                                     const float* __restrict__ comp,
                                                     float* __restrict__ agg, int n) {
    int node = blockIdx.x * 4 + (threadIdx.x >> 6);
    int lane = threadIdx.x & 63;
    if (node >= n) return;
    int s0 = off[node], s1 = off[node + 1];
    const int* cb = cnt + node * NREL;
    float2 a0 = {0, 0}, a1 = {0, 0}, a2 = {0, 0}, a3 = {0, 0};
    for (int i = s0; i < s1; i++) {
        int p = elist[i];
        int s = p >> 4, t = p & 15;
        float nrm = 1.0f / fmaxf((float)cb[t], 1.0f);
        float2 v = *(const float2*)(x + (size_t)s * DIM + lane * 2);
        float c0 = comp[t * NB + 0] * nrm;
        float c1 = comp[t * NB + 1] * nrm;
        float c2 = comp[t * NB + 2] * nrm;
        float c3 = comp[t * NB + 3] * nrm;
        a0.x = fmaf(c0, v.x, a0.x); a0.y = fmaf(c0, v.y, a0.y);
        a1.x = fmaf(c1, v.x, a1.x); a1.y = fmaf(c1, v.y, a1.y);
        a2.x = fmaf(c2, v.x, a2.x); a2.y = fmaf(c2, v.y, a2.y);
        a3.x = fmaf(c3, v.x, a3.x); a3.y = fmaf(c3, v.y, a3.y);
    }
    float* o = agg + (size_t)node * (NB * DIM) + lane * 2;
    *(float2*)(o + 0 * DIM) = a0;
    *(float2*)(o + 1 * DIM) = a1;
    *(float2*)(o + 2 * DIM) = a2;
    *(float2*)(o + 3 * DIM) = a3;
}

// ---------------- split-precision MFMA GEMM ----------------
// out(M,128) = [x|agg](M,640) @ W + bias, fp32 in/out.
// A,W split hi/lo bf16; 3 passes: Ah*Wh + Ah*Wl + Al*Wh (error ~2^-18).
// Block: 128 rows, 4 waves (2x2), wave tile 64x64, BK=32, K=640.
#define LDSK 40  // 32 data + 8 pad shorts; row stride 80B (16B-aligned)
__global__ __launch_bounds__(256) void k_gemm(const float* __restrict__ x,
                                              const float* __restrict__ agg,
                                              const unsigned short* __restrict__ Wh,
                                              const unsigned short* __restrict__ Wl,
                                              const float* __restrict__ bias,
                                              float* __restrict__ out, int relu) {
    __shared__ __align__(16) short Ah[128 * LDSK];
    __shared__ __align__(16) short Al[128 * LDSK];
    __shared__ __align__(16) short Bh[128 * LDSK];
    __shared__ __align__(16) short Bl[128 * LDSK];
    int tid = threadIdx.x;
    int lane = tid & 63, wid = tid >> 6;
    int wave_m = wid >> 1, wave_n = wid & 1;
    int l15 = lane & 15, quad = lane >> 4;
    int row0 = blockIdx.x * 128;

    int srow = tid >> 1, skh = (tid & 1) * 16;

    f32x4 acc[4][4] = {};
    for (int k0 = 0; k0 < 640; k0 += 32) {
        // stage A: 16 fp32 per thread -> hi/lo short8 pairs
        {
            int rg = row0 + srow;
            float4 q0 = {0, 0, 0, 0}, q1 = q0, q2 = q0, q3 = q0;
            if (rg < N2) {
                const float* src = (k0 < 128) ? (x + (size_t)rg * 128 + k0 + skh)
                                              : (agg + (size_t)rg * 512 + (k0 - 128) + skh);
                q0 = *(const float4*)(src + 0);
                q1 = *(const float4*)(src + 4);
                q2 = *(const float4*)(src + 8);
                q3 = *(const float4*)(src + 12);
            }
            short8 h0, l0, h1, l1;
            split8(q0, q1, h0, l0);
            split8(q2, q3, h1, l1);
            *(short8*)(&Ah[srow * LDSK + skh]) = h0;
            *(short8*)(&Ah[srow * LDSK + skh + 8]) = h1;
            *(short8*)(&Al[srow * LDSK + skh]) = l0;
            *(short8*)(&Al[srow * LDSK + skh + 8]) = l1;
        }
        // stage B: prepped bf16 hi/lo
        {
            const unsigned short* sh = Wh + (size_t)srow * 640 + k0 + skh;
            const unsigned short* sl = Wl + (size_t)srow * 640 + k0 + skh;
            *(short8*)(&Bh[srow * LDSK + skh]) = *(const short8*)(sh);
            *(short8*)(&Bh[srow * LDSK + skh + 8]) = *(const short8*)(sh + 8);
            *(short8*)(&Bl[srow * LDSK + skh]) = *(const short8*)(sl);
            *(short8*)(&Bl[srow * LDSK + skh + 8]) = *(const short8*)(sl + 8);
        }
        __syncthreads();
        short8 ah[4], al[4], bh[4], bl[4];
#pragma unroll
        for (int i = 0; i < 4; i++) {
            int ro = (wave_m * 64 + i * 16 + l15) * LDSK + quad * 8;
            ah[i] = *(const short8*)(&Ah[ro]);
            al[i] = *(const short8*)(&Al[ro]);
        }
#pragma unroll
        for (int j = 0; j < 4; j++) {
            int ro = (wave_n * 64 + j * 16 + l15) * LDSK + quad * 8;
            bh[j] = *(const short8*)(&Bh[ro]);
            bl[j] = *(const short8*)(&Bl[ro]);
        }
#pragma unroll
        for (int i = 0; i < 4; i++)
#pragma unroll
            for (int j = 0; j < 4; j++) {
                acc[i][j] = __builtin_amdgcn_mfma_f32_16x16x32_bf16(al[i], bh[j], acc[i][j], 0, 0, 0);
                acc[i][j] = __builtin_amdgcn_mfma_f32_16x16x32_bf16(ah[i], bl[j], acc[i][j], 0, 0, 0);
                acc[i][j] = __builtin_amdgcn_mfma_f32_16x16x32_bf16(ah[i], bh[j], acc[i][j], 0, 0, 0);
            }
        __syncthreads();
    }
    // epilogue: C layout col=lane&15, row=quad*4+reg
#pragma unroll
    for (int j = 0; j < 4; j++) {
        int gcol = wave_n * 64 + j * 16 + l15;
        float bv = bias[gcol];
#pragma unroll
        for (int i = 0; i < 4; i++) {
            int grow_base = row0 + wave_m * 64 + i * 16 + quad * 4;
#pragma unroll
            for (int r = 0; r < 4; r++) {
                int grow = grow_base + r;
                if (grow >= N2) continue;
                float v = acc[i][j][r] + bv;
                if (relu) v = fmaxf(v, 0.f);
                out[(size_t)grow * 128 + gcol] = v;
            }
        }
    }
}

// ---------------- logits + softmax: one wave per row (fp32) ----------------
__global__ __launch_bounds__(256) void k_logits(const float* __restrict__ h2,
                                                const float* __restrict__ tyw_t,
                                                float* __restrict__ out, int M) {
    __shared__ __align__(16) float tyl[DIM * LCOM + 64];
    __shared__ __align__(16) float xs[16][DIM];
    int tid = threadIdx.x;
    for (int i = tid; i < DIM * LCOM; i += 256) tyl[i] = tyw_t[i];
    int base = blockIdx.x * 16;
    for (int i = tid; i < 16 * DIM; i += 256) {
        int r = i >> 7, d = i & 127;
        int rg = base + r;
        xs[r][d] = (rg < M) ? h2[(size_t)rg * DIM + d] : 0.f;
    }
    __syncthreads();
    int wave = tid >> 6, lane = tid & 63;
#pragma unroll
    for (int rr = 0; rr < 4; rr++) {
        int r = wave * 4 + rr;
        int row = base + r;
        if (row >= M) continue;
        float acc0 = 0.f, acc1 = 0.f;
#pragma unroll 8
        for (int d = 0; d < DIM; d++) {
            float xv = xs[r][d];
            acc0 = fmaf(xv, tyl[d * LCOM + lane], acc0);
            acc1 = fmaf(xv, tyl[d * LCOM + 64 + lane], acc1);
        }
        float m = fmaxf(acc0, (lane < 36) ? acc1 : -INFINITY);
        for (int off = 32; off; off >>= 1) m = fmaxf(m, __shfl_xor(m, off, 64));
        float e0 = __expf(acc0 - m);
        float e1 = (lane < 36) ? __expf(acc1 - m) : 0.f;
        float s = e0 + e1;
        for (int off = 32; off; off >>= 1) s += __shfl_xor(s, off, 64);
        float inv = 1.0f / s;
        out[(size_t)row * LCOM + lane] = e0 * inv;
        if (lane < 36) out[(size_t)row * LCOM + 64 + lane] = e1 * inv;
    }
}

extern "C" void kernel_launch(void* const* d_in, const int* in_sizes, int n_in,
                              void* d_out, int out_size, void* d_ws, size_t ws_size,
                              hipStream_t stream) {
    const int* ei2 = (const int*)d_in[0];
    const int* et2 = (const int*)d_in[1];
    const int* ei1 = (const int*)d_in[2];
    const int* lc = (const int*)d_in[3];
    const float* emb = (const float*)d_in[4];
    const float* basis1 = (const float*)d_in[5];
    const float* comp1 = (const float*)d_in[6];
    const float* root1 = (const float*)d_in[7];
    const float* bias1 = (const float*)d_in[8];
    const float* basis2 = (const float*)d_in[9];
    const float* comp2 = (const float*)d_in[10];
    const float* root2 = (const float*)d_in[11];
    const float* bias2 = (const float*)d_in[12];
    const float* wts = (const float*)d_in[13];
    float* out = (float*)d_out;
    int E2 = in_sizes[0] / 2, E1 = in_sizes[2] / 2;

    float* ws = (float*)d_ws;
    float* xg1 = ws;                       // 6,400,000 (50000x128; reused as h2)
    float* h1 = xg1 + 6400000;             // 6,400,000
    float* agg = h1 + 6400000;             // 25,600,000
    float* tyw = agg + 25600000;           // 12,800
    unsigned short* Wh1 = (unsigned short*)(tyw + 12800);  // 81,920 shorts
    unsigned short* Wl1 = Wh1 + 81920;
    unsigned short* Wh2 = Wl1 + 81920;
    unsigned short* Wl2 = Wh2 + 81920;
    int* ipool = (int*)(Wl2 + 81920);
    int* deg1 = ipool;                     // 60,000
    int* off1 = deg1 + 60000;              // 60,001
    int* cur1 = off1 + 60001;              // 60,000
    int* elist1 = cur1 + 60000;            // 800,000
    int* cnt2 = elist1 + 800000;           // 800,000
    int* deg2 = cnt2 + 800000;             // 50,000
    int* off2 = deg2 + 50000;              // 50,001
    int* cur2 = off2 + 50001;              // 50,000
    int* elist2 = cur2 + 50000;            // 800,000
    float* h2 = xg1;                       // alias (xg1 dead after gemm1; tyw reads emb)

    // ---- weight prep ----
    k_prep_w<<<(640 * 128 + 255) / 256, 256, 0, stream>>>(root1, basis1, Wh1, Wl1);
    k_prep_w<<<(640 * 128 + 255) / 256, 256, 0, stream>>>(root2, basis2, Wh2, Wl2);

    // ---- g1 CSR + concept layer (rows < 50000) + tyw (on-the-fly rows) ----
    hipMemsetAsync(deg1, 0, 60000 * sizeof(int), stream);
    k_hist_deg<<<(E1 + 255) / 256, 256, 0, stream>>>(ei1, deg1, E1);
    k_scan<<<1, 1024, 0, stream>>>(deg1, off1, cur1, N1);
    k_csr_scatter1<<<(E1 + 255) / 256, 256, 0, stream>>>(ei1, cur1, elist1, E1);
    k_concept_gather<<<(N2 + 3) / 4, 256, 0, stream>>>(emb, off1, elist1, xg1, N2);
    k_tyw<<<LCOM, 64, 0, stream>>>(emb, off1, elist1, lc, wts, tyw);

    // ---- g2 CSR ----
    hipMemsetAsync(cnt2, 0, 800000 * sizeof(int), stream);
    k_hist_dt<<<(E2 + 255) / 256, 256, 0, stream>>>(ei2, et2, cnt2, E2);
    k_deg_from_cnt<<<(N2 + 255) / 256, 256, 0, stream>>>(cnt2, deg2, N2);
    k_scan<<<1, 1024, 0, stream>>>(deg2, off2, cur2, N2);
    k_csr_scatter2<<<(E2 + 255) / 256, 256, 0, stream>>>(ei2, et2, cur2, elist2, E2);

    // ---- rgcn layer 1 ----
    k_rgcn_gather<<<(N2 + 3) / 4, 256, 0, stream>>>(xg1, off2, elist2, cnt2, comp1, agg, N2);
    k_gemm<<<(N2 + 127) / 128, 256, 0, stream>>>(xg1, agg, Wh1, Wl1, bias1, h1, 1);

    // ---- rgcn layer 2 ----
    k_rgcn_gather<<<(N2 + 3) / 4, 256, 0, stream>>>(h1, off2, elist2, cnt2, comp2, agg, N2);
    k_gemm<<<(N2 + 127) / 128, 256, 0, stream>>>(h1, agg, Wh2, Wl2, bias2, h2, 0);

    // ---- logits + softmax ----
    k_logits<<<(N2 + 15) / 16, 256, 0, stream>>>(h2, tyw, out, N2);
}

// Round 5
// 741.617 us; speedup vs baseline: 16.8141x; 1.3617x over previous
//
#include <hip/hip_runtime.h>
#include <hip/hip_bf16.h>
#include <math.h>

#define N1 60000
#define N2 50000
#define DIM 128
#define NREL 16
#define NB 4
#define LCOM 100

typedef __attribute__((ext_vector_type(8))) short short8;
typedef __attribute__((ext_vector_type(4))) float f32x4;

__device__ __forceinline__ float bf2f(unsigned short u) {
    union { unsigned int i; float f; } c; c.i = ((unsigned int)u) << 16; return c.f;
}
__device__ __forceinline__ unsigned short f2bf(float f) {
    union { float f; unsigned int i; } c; c.f = f;
    unsigned int r = c.i + 0x7FFF + ((c.i >> 16) & 1);  // RNE
    return (unsigned short)(r >> 16);
}
__device__ __forceinline__ void split8(float4 a, float4 b, short8& h, short8& l) {
    float f[8] = {a.x, a.y, a.z, a.w, b.x, b.y, b.z, b.w};
#pragma unroll
    for (int j = 0; j < 8; j++) {
        unsigned short hh = f2bf(f[j]);
        h[j] = (short)hh;
        l[j] = (short)f2bf(f[j] - bf2f(hh));
    }
}

// ---------------- weight prep: W=[root;basis_flat] (640x128) -> Wt_hi/lo[n*640+k] ----------------
__global__ void k_prep_w(const float* __restrict__ root, const float* __restrict__ basis,
                         unsigned short* __restrict__ Wh, unsigned short* __restrict__ Wl) {
    int t = blockIdx.x * blockDim.x + threadIdx.x;
    if (t >= 640 * 128) return;
    int k = t >> 7, n = t & 127;
    float v = (k < 128) ? root[k * 128 + n] : basis[(k - 128) * 128 + n];
    unsigned short h = f2bf(v);
    Wh[n * 640 + k] = h;
    Wl[n * 640 + k] = f2bf(v - bf2f(h));
}

// ---------------- histograms ----------------
__global__ void k_hist_deg(const int* __restrict__ ei, int* __restrict__ deg, int E) {
    int e = blockIdx.x * blockDim.x + threadIdx.x;
    if (e >= E) return;
    atomicAdd(deg + ei[E + e], 1);
}

__global__ void k_hist_dt(const int* __restrict__ ei, const int* __restrict__ et,
                          int* __restrict__ cnt, int E) {
    int e = blockIdx.x * blockDim.x + threadIdx.x;
    if (e >= E) return;
    atomicAdd(cnt + ei[E + e] * NREL + et[e], 1);
}

__global__ void k_deg_from_cnt(const int* __restrict__ cnt, int* __restrict__ deg, int n) {
    int i = blockIdx.x * blockDim.x + threadIdx.x;
    if (i >= n) return;
    int s = 0;
#pragma unroll
    for (int t = 0; t < NREL; t++) s += cnt[i * NREL + t];
    deg[i] = s;
}

// ---------------- hierarchical exclusive scan (3 phases) ----------------
// phase 1: per-block (1024 elems) partial sums
__global__ __launch_bounds__(256) void k_scan_p1(const int* __restrict__ in,
                                                 int* __restrict__ bsum, int n) {
    __shared__ int red[256];
    int base = blockIdx.x * 1024;
    int tid = threadIdx.x;
    int s = 0;
#pragma unroll
    for (int j = 0; j < 4; j++) {
        int i = base + tid * 4 + j;
        if (i < n) s += in[i];
    }
    red[tid] = s;
    __syncthreads();
    for (int d = 128; d; d >>= 1) {
        if (tid < d) red[tid] += red[tid + d];
        __syncthreads();
    }
    if (tid == 0) bsum[blockIdx.x] = red[0];
}

// phase 2: exclusive scan of nb (<=64) block sums; writes off[n]=total
__global__ __launch_bounds__(64) void k_scan_p2(const int* __restrict__ bsum,
                                                int* __restrict__ boff,
                                                int* __restrict__ off, int nb, int n) {
    __shared__ int s[64];
    int tid = threadIdx.x;
    int v = (tid < nb) ? bsum[tid] : 0;
    s[tid] = v;
    __syncthreads();
    for (int d = 1; d < 64; d <<= 1) {
        int t = (tid >= d) ? s[tid - d] : 0;
        __syncthreads();
        s[tid] += t;
        __syncthreads();
    }
    if (tid < nb) boff[tid] = s[tid] - v;
    if (tid == 63) off[n] = s[63];
}

// phase 3: per-block exclusive scan + block offset; writes off & cur
__global__ __launch_bounds__(256) void k_scan_p3(const int* __restrict__ in,
                                                 const int* __restrict__ boff,
                                                 int* __restrict__ off,
                                                 int* __restrict__ cur, int n) {
    __shared__ int red[256];
    int base = blockIdx.x * 1024;
    int tid = threadIdx.x;
    int v[4];
    int s = 0;
#pragma unroll
    for (int j = 0; j < 4; j++) {
        int i = base + tid * 4 + j;
        v[j] = (i < n) ? in[i] : 0;
        s += v[j];
    }
    red[tid] = s;
    __syncthreads();
    for (int d = 1; d < 256; d <<= 1) {
        int t = (tid >= d) ? red[tid - d] : 0;
        __syncthreads();
        red[tid] += t;
        __syncthreads();
    }
    int run = boff[blockIdx.x] + red[tid] - s;
#pragma unroll
    for (int j = 0; j < 4; j++) {
        int i = base + tid * 4 + j;
        if (i < n) {
            off[i] = run; cur[i] = run;
            run += v[j];
        }
    }
}

// ---------------- CSR scatter ----------------
__global__ void k_csr_scatter1(const int* __restrict__ ei, int* __restrict__ cur,
                               int* __restrict__ elist, int E) {
    int e = blockIdx.x * blockDim.x + threadIdx.x;
    if (e >= E) return;
    int pos = atomicAdd(cur + ei[E + e], 1);
    elist[pos] = ei[e];
}

__global__ void k_csr_scatter2(const int* __restrict__ ei, const int* __restrict__ et,
                               int* __restrict__ cur, int* __restrict__ elist, int E) {
    int e = blockIdx.x * blockDim.x + threadIdx.x;
    if (e >= E) return;
    int pos = atomicAdd(cur + ei[E + e], 1);
    elist[pos] = (ei[e] << 4) | et[e];
}

// ---------------- concept layer: gather-mean (fp32), rows < n only ----------------
__global__ __launch_bounds__(256) void k_concept_gather(const float* __restrict__ emb,
                                                        const int* __restrict__ off,
                                                        const int* __restrict__ elist,
                                                        float* __restrict__ xg1, int n) {
    int node = blockIdx.x * 4 + (threadIdx.x >> 6);
    int lane = threadIdx.x & 63;
    if (node >= n) return;
    int s0 = off[node], s1 = off[node + 1];
    float2 acc = {0.f, 0.f};
    int i = s0;
    for (; i + 1 < s1; i += 2) {
        int sa = elist[i], sb = elist[i + 1];
        float2 va = *(const float2*)(emb + (size_t)sa * DIM + lane * 2);
        float2 vb = *(const float2*)(emb + (size_t)sb * DIM + lane * 2);
        acc.x += va.x + vb.x; acc.y += va.y + vb.y;
    }
    if (i < s1) {
        int sa = elist[i];
        float2 va = *(const float2*)(emb + (size_t)sa * DIM + lane * 2);
        acc.x += va.x; acc.y += va.y;
    }
    float inv = 1.0f / (float)max(s1 - s0, 1);
    float2 e = *(const float2*)(emb + (size_t)node * DIM + lane * 2);
    float2 o = {fmaxf(e.x + acc.x * inv, 0.f), fmaxf(e.y + acc.y * inv, 0.f)};
    *(float2*)(xg1 + (size_t)node * DIM + lane * 2) = o;
}

// ---------------- tyw: compute concept row lc[l] on the fly ----------------
__global__ __launch_bounds__(64) void k_tyw(const float* __restrict__ emb,
                                            const int* __restrict__ off,
                                            const int* __restrict__ elist,
                                            const int* __restrict__ lc,
                                            const float* __restrict__ w,
                                            float* __restrict__ tyw_t) {
    int l = blockIdx.x;
    int lane = threadIdx.x;
    int row = lc[l];
    int s0 = off[row], s1 = off[row + 1];
    float2 acc = {0.f, 0.f};
    for (int i = s0; i < s1; i++) {
        int s = elist[i];
        float2 v = *(const float2*)(emb + (size_t)s * DIM + lane * 2);
        acc.x += v.x; acc.y += v.y;
    }
    float inv = 1.0f / (float)max(s1 - s0, 1);
    float2 e = *(const float2*)(emb + (size_t)row * DIM + lane * 2);
    int d0 = lane * 2;
    tyw_t[(size_t)d0 * LCOM + l] = fmaxf(e.x + acc.x * inv, 0.f) * w[d0];
    tyw_t[(size_t)(d0 + 1) * LCOM + l] = fmaxf(e.y + acc.y * inv, 0.f) * w[d0 + 1];
}

// ---------------- rgcn aggregation: gather (fp32), unroll x2 ----------------
__global__ __launch_bounds__(256) void k_rgcn_gather(const float* __restrict__ x,
                                                     const int* __restrict__ off,
                                                     const int* __restrict__ elist,
                                                     const int* __restrict__ cnt,
                                                     const float* __restrict__ comp,
                                                     float* __restrict__ agg, int n) {
    int node = blockIdx.x * 4 + (threadIdx.x >> 6);
    int lane = threadIdx.x & 63;
    if (node >= n) return;
    int s0 = off[node], s1 = off[node + 1];
    const int* cb = cnt + node * NREL;
    float2 a0 = {0, 0}, a1 = {0, 0}, a2 = {0, 0}, a3 = {0, 0};
    int i = s0;
    for (; i + 1 < s1; i += 2) {
        int pa = elist[i], pb = elist[i + 1];
        int sa = pa >> 4, ta = pa & 15;
        int sb = pb >> 4, tb = pb & 15;
        float2 va = *(const float2*)(x + (size_t)sa * DIM + lane * 2);
        float2 vb = *(const float2*)(x + (size_t)sb * DIM + lane * 2);
        float na = 1.0f / fmaxf((float)cb[ta], 1.0f);
        float nb = 1.0f / fmaxf((float)cb[tb], 1.0f);
        float c;
        c = comp[ta * NB + 0] * na; a0.x = fmaf(c, va.x, a0.x); a0.y = fmaf(c, va.y, a0.y);
        c = comp[ta * NB + 1] * na; a1.x = fmaf(c, va.x, a1.x); a1.y = fmaf(c, va.y, a1.y);
        c = comp[ta * NB + 2] * na; a2.x = fmaf(c, va.x, a2.x); a2.y = fmaf(c, va.y, a2.y);
        c = comp[ta * NB + 3] * na; a3.x = fmaf(c, va.x, a3.x); a3.y = fmaf(c, va.y, a3.y);
        c = comp[tb * NB + 0] * nb; a0.x = fmaf(c, vb.x, a0.x); a0.y = fmaf(c, vb.y, a0.y);
        c = comp[tb * NB + 1] * nb; a1.x = fmaf(c, vb.x, a1.x); a1.y = fmaf(c, vb.y, a1.y);
        c = comp[tb * NB + 2] * nb; a2.x = fmaf(c, vb.x, a2.x); a2.y = fmaf(c, vb.y, a2.y);
        c = comp[tb * NB + 3] * nb; a3.x = fmaf(c, vb.x, a3.x); a3.y = fmaf(c, vb.y, a3.y);
    }
    if (i < s1) {
        int pa = elist[i];
        int sa = pa >> 4, ta = pa & 15;
        float2 va = *(const float2*)(x + (size_t)sa * DIM + lane * 2);
        float na = 1.0f / fmaxf((float)cb[ta], 1.0f);
        float c;
        c = comp[ta * NB + 0] * na; a0.x = fmaf(c, va.x, a0.x); a0.y = fmaf(c, va.y, a0.y);
        c = comp[ta * NB + 1] * na; a1.x = fmaf(c, va.x, a1.x); a1.y = fmaf(c, va.y, a1.y);
        c = comp[ta * NB + 2] * na; a2.x = fmaf(c, va.x, a2.x); a2.y = fmaf(c, va.y, a2.y);
        c = comp[ta * NB + 3] * na; a3.x = fmaf(c, va.x, a3.x); a3.y = fmaf(c, va.y, a3.y);
    }
    float* o = agg + (size_t)node * (NB * DIM) + lane * 2;
    *(float2*)(o + 0 * DIM) = a0;
    *(float2*)(o + 1 * DIM) = a1;
    *(float2*)(o + 2 * DIM) = a2;
    *(float2*)(o + 3 * DIM) = a3;
}

// ---------------- split-precision MFMA GEMM ----------------
#define LDSK 40
__global__ __launch_bounds__(256) void k_gemm(const float* __restrict__ x,
                                              const float* __restrict__ agg,
                                              const unsigned short* __restrict__ Wh,
                                              const unsigned short* __restrict__ Wl,
                                              const float* __restrict__ bias,
                                              float* __restrict__ out, int relu) {
    __shared__ __align__(16) short Ah[128 * LDSK];
    __shared__ __align__(16) short Al[128 * LDSK];
    __shared__ __align__(16) short Bh[128 * LDSK];
    __shared__ __align__(16) short Bl[128 * LDSK];
    int tid = threadIdx.x;
    int lane = tid & 63, wid = tid >> 6;
    int wave_m = wid >> 1, wave_n = wid & 1;
    int l15 = lane & 15, quad = lane >> 4;
    int row0 = blockIdx.x * 128;

    int srow = tid >> 1, skh = (tid & 1) * 16;

    f32x4 acc[4][4] = {};
    for (int k0 = 0; k0 < 640; k0 += 32) {
        {
            int rg = row0 + srow;
            float4 q0 = {0, 0, 0, 0}, q1 = q0, q2 = q0, q3 = q0;
            if (rg < N2) {
                const float* src = (k0 < 128) ? (x + (size_t)rg * 128 + k0 + skh)
                                              : (agg + (size_t)rg * 512 + (k0 - 128) + skh);
                q0 = *(const float4*)(src + 0);
                q1 = *(const float4*)(src + 4);
                q2 = *(const float4*)(src + 8);
                q3 = *(const float4*)(src + 12);
            }
            short8 h0, l0, h1, l1;
            split8(q0, q1, h0, l0);
            split8(q2, q3, h1, l1);
            *(short8*)(&Ah[srow * LDSK + skh]) = h0;
            *(short8*)(&Ah[srow * LDSK + skh + 8]) = h1;
            *(short8*)(&Al[srow * LDSK + skh]) = l0;
            *(short8*)(&Al[srow * LDSK + skh + 8]) = l1;
        }
        {
            const unsigned short* sh = Wh + (size_t)srow * 640 + k0 + skh;
            const unsigned short* sl = Wl + (size_t)srow * 640 + k0 + skh;
            *(short8*)(&Bh[srow * LDSK + skh]) = *(const short8*)(sh);
            *(short8*)(&Bh[srow * LDSK + skh + 8]) = *(const short8*)(sh + 8);
            *(short8*)(&Bl[srow * LDSK + skh]) = *(const short8*)(sl);
            *(short8*)(&Bl[srow * LDSK + skh + 8]) = *(const short8*)(sl + 8);
        }
        __syncthreads();
        short8 ah[4], al[4], bh[4], bl[4];
#pragma unroll
        for (int i = 0; i < 4; i++) {
            int ro = (wave_m * 64 + i * 16 + l15) * LDSK + quad * 8;
            ah[i] = *(const short8*)(&Ah[ro]);
            al[i] = *(const short8*)(&Al[ro]);
        }
#pragma unroll
        for (int j = 0; j < 4; j++) {
            int ro = (wave_n * 64 + j * 16 + l15) * LDSK + quad * 8;
            bh[j] = *(const short8*)(&Bh[ro]);
            bl[j] = *(const short8*)(&Bl[ro]);
        }
#pragma unroll
        for (int i = 0; i < 4; i++)
#pragma unroll
            for (int j = 0; j < 4; j++) {
                acc[i][j] = __builtin_amdgcn_mfma_f32_16x16x32_bf16(al[i], bh[j], acc[i][j], 0, 0, 0);
                acc[i][j] = __builtin_amdgcn_mfma_f32_16x16x32_bf16(ah[i], bl[j], acc[i][j], 0, 0, 0);
                acc[i][j] = __builtin_amdgcn_mfma_f32_16x16x32_bf16(ah[i], bh[j], acc[i][j], 0, 0, 0);
            }
        __syncthreads();
    }
#pragma unroll
    for (int j = 0; j < 4; j++) {
        int gcol = wave_n * 64 + j * 16 + l15;
        float bv = bias[gcol];
#pragma unroll
        for (int i = 0; i < 4; i++) {
            int grow_base = row0 + wave_m * 64 + i * 16 + quad * 4;
#pragma unroll
            for (int r = 0; r < 4; r++) {
                int grow = grow_base + r;
                if (grow >= N2) continue;
                float v = acc[i][j][r] + bv;
                if (relu) v = fmaxf(v, 0.f);
                out[(size_t)grow * 128 + gcol] = v;
            }
        }
    }
}

// ---------------- logits + softmax: one wave per row (fp32) ----------------
__global__ __launch_bounds__(256) void k_logits(const float* __restrict__ h2,
                                                const float* __restrict__ tyw_t,
                                                float* __restrict__ out, int M) {
    __shared__ __align__(16) float tyl[DIM * LCOM + 64];
    __shared__ __align__(16) float xs[16][DIM];
    int tid = threadIdx.x;
    for (int i = tid; i < DIM * LCOM; i += 256) tyl[i] = tyw_t[i];
    int base = blockIdx.x * 16;
    for (int i = tid; i < 16 * DIM; i += 256) {
        int r = i >> 7, d = i & 127;
        int rg = base + r;
        xs[r][d] = (rg < M) ? h2[(size_t)rg * DIM + d] : 0.f;
    }
    __syncthreads();
    int wave = tid >> 6, lane = tid & 63;
#pragma unroll
    for (int rr = 0; rr < 4; rr++) {
        int r = wave * 4 + rr;
        int row = base + r;
        if (row >= M) continue;
        float acc0 = 0.f, acc1 = 0.f;
#pragma unroll 8
        for (int d = 0; d < DIM; d++) {
            float xv = xs[r][d];
            acc0 = fmaf(xv, tyl[d * LCOM + lane], acc0);
            acc1 = fmaf(xv, tyl[d * LCOM + 64 + lane], acc1);
        }
        float m = fmaxf(acc0, (lane < 36) ? acc1 : -INFINITY);
        for (int off = 32; off; off >>= 1) m = fmaxf(m, __shfl_xor(m, off, 64));
        float e0 = __expf(acc0 - m);
        float e1 = (lane < 36) ? __expf(acc1 - m) : 0.f;
        float s = e0 + e1;
        for (int off = 32; off; off >>= 1) s += __shfl_xor(s, off, 64);
        float inv = 1.0f / s;
        out[(size_t)row * LCOM + lane] = e0 * inv;
        if (lane < 36) out[(size_t)row * LCOM + 64 + lane] = e1 * inv;
    }
}

extern "C" void kernel_launch(void* const* d_in, const int* in_sizes, int n_in,
                              void* d_out, int out_size, void* d_ws, size_t ws_size,
                              hipStream_t stream) {
    const int* ei2 = (const int*)d_in[0];
    const int* et2 = (const int*)d_in[1];
    const int* ei1 = (const int*)d_in[2];
    const int* lc = (const int*)d_in[3];
    const float* emb = (const float*)d_in[4];
    const float* basis1 = (const float*)d_in[5];
    const float* comp1 = (const float*)d_in[6];
    const float* root1 = (const float*)d_in[7];
    const float* bias1 = (const float*)d_in[8];
    const float* basis2 = (const float*)d_in[9];
    const float* comp2 = (const float*)d_in[10];
    const float* root2 = (const float*)d_in[11];
    const float* bias2 = (const float*)d_in[12];
    const float* wts = (const float*)d_in[13];
    float* out = (float*)d_out;
    int E2 = in_sizes[0] / 2, E1 = in_sizes[2] / 2;

    float* ws = (float*)d_ws;
    float* xg1 = ws;                       // 6,400,000 (50000x128; reused as h2)
    float* h1 = xg1 + 6400000;             // 6,400,000
    float* agg = h1 + 6400000;             // 25,600,000
    float* tyw = agg + 25600000;           // 12,800
    unsigned short* Wh1 = (unsigned short*)(tyw + 12800);
    unsigned short* Wl1 = Wh1 + 81920;
    unsigned short* Wh2 = Wl1 + 81920;
    unsigned short* Wl2 = Wh2 + 81920;
    int* ipool = (int*)(Wl2 + 81920);
    int* deg1 = ipool;                     // 60,000
    int* off1 = deg1 + 60000;              // 60,001
    int* cur1 = off1 + 60001;              // 60,000
    int* elist1 = cur1 + 60000;            // 800,000
    int* cnt2 = elist1 + 800000;           // 800,000
    int* deg2 = cnt2 + 800000;             // 50,000
    int* off2 = deg2 + 50000;              // 50,001
    int* cur2 = off2 + 50001;              // 50,000
    int* elist2 = cur2 + 50000;            // 800,000
    int* bsum1 = elist2 + 800000;          // 64
    int* boff1 = bsum1 + 64;               // 64
    int* bsum2 = boff1 + 64;               // 64
    int* boff2 = bsum2 + 64;               // 64
    float* h2 = xg1;

    const int NB1 = (N1 + 1023) / 1024;    // 59
    const int NB2 = (N2 + 1023) / 1024;    // 49

    // ---- weight prep ----
    k_prep_w<<<(640 * 128 + 255) / 256, 256, 0, stream>>>(root1, basis1, Wh1, Wl1);
    k_prep_w<<<(640 * 128 + 255) / 256, 256, 0, stream>>>(root2, basis2, Wh2, Wl2);

    // ---- g1 CSR + concept layer (rows < 50000) + tyw ----
    hipMemsetAsync(deg1, 0, 60000 * sizeof(int), stream);
    k_hist_deg<<<(E1 + 255) / 256, 256, 0, stream>>>(ei1, deg1, E1);
    k_scan_p1<<<NB1, 256, 0, stream>>>(deg1, bsum1, N1);
    k_scan_p2<<<1, 64, 0, stream>>>(bsum1, boff1, off1, NB1, N1);
    k_scan_p3<<<NB1, 256, 0, stream>>>(deg1, boff1, off1, cur1, N1);
    k_csr_scatter1<<<(E1 + 255) / 256, 256, 0, stream>>>(ei1, cur1, elist1, E1);
    k_concept_gather<<<(N2 + 3) / 4, 256, 0, stream>>>(emb, off1, elist1, xg1, N2);
    k_tyw<<<LCOM, 64, 0, stream>>>(emb, off1, elist1, lc, wts, tyw);

    // ---- g2 CSR ----
    hipMemsetAsync(cnt2, 0, 800000 * sizeof(int), stream);
    k_hist_dt<<<(E2 + 255) / 256, 256, 0, stream>>>(ei2, et2, cnt2, E2);
    k_deg_from_cnt<<<(N2 + 255) / 256, 256, 0, stream>>>(cnt2, deg2, N2);
    k_scan_p1<<<NB2, 256, 0, stream>>>(deg2, bsum2, N2);
    k_scan_p2<<<1, 64, 0, stream>>>(bsum2, boff2, off2, NB2, N2);
    k_scan_p3<<<NB2, 256, 0, stream>>>(deg2, boff2, off2, cur2, N2);
    k_csr_scatter2<<<(E2 + 255) / 256, 256, 0, stream>>>(ei2, et2, cur2, elist2, E2);

    // ---- rgcn layer 1 ----
    k_rgcn_gather<<<(N2 + 3) / 4, 256, 0, stream>>>(xg1, off2, elist2, cnt2, comp1, agg, N2);
    k_gemm<<<(N2 + 127) / 128, 256, 0, stream>>>(xg1, agg, Wh1, Wl1, bias1, h1, 1);

    // ---- rgcn layer 2 ----
    k_rgcn_gather<<<(N2 + 3) / 4, 256, 0, stream>>>(h1, off2, elist2, cnt2, comp2, agg, N2);
    k_gemm<<<(N2 + 127) / 128, 256, 0, stream>>>(h1, agg, Wh2, Wl2, bias2, h2, 0);

    // ---- logits + softmax ----
    k_logits<<<(N2 + 15) / 16, 256, 0, stream>>>(h2, tyw, out, N2);
}

// Round 6
// 653.588 us; speedup vs baseline: 19.0787x; 1.1347x over previous
//
#include <hip/hip_runtime.h>
#include <hip/hip_bf16.h>
#include <math.h>

#define N1 60000
#define N2 50000
#define DIM 128
#define NREL 16
#define NB 4
#define LCOM 100
#define LPAD 112  // LCOM padded to 7x16 for MFMA N-tiles

typedef __attribute__((ext_vector_type(8))) short short8;
typedef __attribute__((ext_vector_type(4))) float f32x4;

__device__ __forceinline__ float bf2f(unsigned short u) {
    union { unsigned int i; float f; } c; c.i = ((unsigned int)u) << 16; return c.f;
}
__device__ __forceinline__ unsigned short f2bf(float f) {
    union { float f; unsigned int i; } c; c.f = f;
    unsigned int r = c.i + 0x7FFF + ((c.i >> 16) & 1);  // RNE
    return (unsigned short)(r >> 16);
}
__device__ __forceinline__ void split8(float4 a, float4 b, short8& h, short8& l) {
    float f[8] = {a.x, a.y, a.z, a.w, b.x, b.y, b.z, b.w};
#pragma unroll
    for (int j = 0; j < 8; j++) {
        unsigned short hh = f2bf(f[j]);
        h[j] = (short)hh;
        l[j] = (short)f2bf(f[j] - bf2f(hh));
    }
}

// ---------------- weight prep: W=[root;basis_flat] (640x128) -> Wt_hi/lo[n*640+k] ----------------
__global__ void k_prep_w(const float* __restrict__ root, const float* __restrict__ basis,
                         unsigned short* __restrict__ Wh, unsigned short* __restrict__ Wl) {
    int t = blockIdx.x * blockDim.x + threadIdx.x;
    if (t >= 640 * 128) return;
    int k = t >> 7, n = t & 127;
    float v = (k < 128) ? root[k * 128 + n] : basis[(k - 128) * 128 + n];
    unsigned short h = f2bf(v);
    Wh[n * 640 + k] = h;
    Wl[n * 640 + k] = f2bf(v - bf2f(h));
}

// ---------------- histograms ----------------
__global__ void k_hist_deg(const int* __restrict__ ei, int* __restrict__ deg, int E) {
    int e = blockIdx.x * blockDim.x + threadIdx.x;
    if (e >= E) return;
    atomicAdd(deg + ei[E + e], 1);
}

__global__ void k_hist_dt(const int* __restrict__ ei, const int* __restrict__ et,
                          int* __restrict__ cnt, int E) {
    int e = blockIdx.x * blockDim.x + threadIdx.x;
    if (e >= E) return;
    atomicAdd(cnt + ei[E + e] * NREL + et[e], 1);
}

__global__ void k_deg_from_cnt(const int* __restrict__ cnt, int* __restrict__ deg, int n) {
    int i = blockIdx.x * blockDim.x + threadIdx.x;
    if (i >= n) return;
    int s = 0;
#pragma unroll
    for (int t = 0; t < NREL; t++) s += cnt[i * NREL + t];
    deg[i] = s;
}

// ---------------- hierarchical exclusive scan (3 phases) ----------------
__global__ __launch_bounds__(256) void k_scan_p1(const int* __restrict__ in,
                                                 int* __restrict__ bsum, int n) {
    __shared__ int red[256];
    int base = blockIdx.x * 1024;
    int tid = threadIdx.x;
    int s = 0;
#pragma unroll
    for (int j = 0; j < 4; j++) {
        int i = base + tid * 4 + j;
        if (i < n) s += in[i];
    }
    red[tid] = s;
    __syncthreads();
    for (int d = 128; d; d >>= 1) {
        if (tid < d) red[tid] += red[tid + d];
        __syncthreads();
    }
    if (tid == 0) bsum[blockIdx.x] = red[0];
}

__global__ __launch_bounds__(64) void k_scan_p2(const int* __restrict__ bsum,
                                                int* __restrict__ boff,
                                                int* __restrict__ off, int nb, int n) {
    __shared__ int s[64];
    int tid = threadIdx.x;
    int v = (tid < nb) ? bsum[tid] : 0;
    s[tid] = v;
    __syncthreads();
    for (int d = 1; d < 64; d <<= 1) {
        int t = (tid >= d) ? s[tid - d] : 0;
        __syncthreads();
        s[tid] += t;
        __syncthreads();
    }
    if (tid < nb) boff[tid] = s[tid] - v;
    if (tid == 63) off[n] = s[63];
}

__global__ __launch_bounds__(256) void k_scan_p3(const int* __restrict__ in,
                                                 const int* __restrict__ boff,
                                                 int* __restrict__ off,
                                                 int* __restrict__ cur, int n) {
    __shared__ int red[256];
    int base = blockIdx.x * 1024;
    int tid = threadIdx.x;
    int v[4];
    int s = 0;
#pragma unroll
    for (int j = 0; j < 4; j++) {
        int i = base + tid * 4 + j;
        v[j] = (i < n) ? in[i] : 0;
        s += v[j];
    }
    red[tid] = s;
    __syncthreads();
    for (int d = 1; d < 256; d <<= 1) {
        int t = (tid >= d) ? red[tid - d] : 0;
        __syncthreads();
        red[tid] += t;
        __syncthreads();
    }
    int run = boff[blockIdx.x] + red[tid] - s;
#pragma unroll
    for (int j = 0; j < 4; j++) {
        int i = base + tid * 4 + j;
        if (i < n) {
            off[i] = run; cur[i] = run;
            run += v[j];
        }
    }
}

// ---------------- CSR scatter ----------------
__global__ void k_csr_scatter1(const int* __restrict__ ei, int* __restrict__ cur,
                               int* __restrict__ elist, int E) {
    int e = blockIdx.x * blockDim.x + threadIdx.x;
    if (e >= E) return;
    int pos = atomicAdd(cur + ei[E + e], 1);
    elist[pos] = ei[e];
}

__global__ void k_csr_scatter2(const int* __restrict__ ei, const int* __restrict__ et,
                               int* __restrict__ cur, int* __restrict__ elist, int E) {
    int e = blockIdx.x * blockDim.x + threadIdx.x;
    if (e >= E) return;
    int pos = atomicAdd(cur + ei[E + e], 1);
    elist[pos] = (ei[e] << 4) | et[e];
}

// ---------------- concept layer: gather-mean (fp32), rows < n only ----------------
__global__ __launch_bounds__(256) void k_concept_gather(const float* __restrict__ emb,
                                                        const int* __restrict__ off,
                                                        const int* __restrict__ elist,
                                                        float* __restrict__ xg1, int n) {
    int node = blockIdx.x * 4 + (threadIdx.x >> 6);
    int lane = threadIdx.x & 63;
    if (node >= n) return;
    int s0 = off[node], s1 = off[node + 1];
    float2 acc = {0.f, 0.f};
    int i = s0;
    for (; i + 1 < s1; i += 2) {
        int sa = elist[i], sb = elist[i + 1];
        float2 va = *(const float2*)(emb + (size_t)sa * DIM + lane * 2);
        float2 vb = *(const float2*)(emb + (size_t)sb * DIM + lane * 2);
        acc.x += va.x + vb.x; acc.y += va.y + vb.y;
    }
    if (i < s1) {
        int sa = elist[i];
        float2 va = *(const float2*)(emb + (size_t)sa * DIM + lane * 2);
        acc.x += va.x; acc.y += va.y;
    }
    float inv = 1.0f / (float)max(s1 - s0, 1);
    float2 e = *(const float2*)(emb + (size_t)node * DIM + lane * 2);
    float2 o = {fmaxf(e.x + acc.x * inv, 0.f), fmaxf(e.y + acc.y * inv, 0.f)};
    *(float2*)(xg1 + (size_t)node * DIM + lane * 2) = o;
}

// ---------------- tyw: concept row lc[l] on the fly -> split bf16 hi/lo, [n][k] layout ----------------
// tyh/tyl: LPAD x 128; rows >= LCOM zeroed.
__global__ __launch_bounds__(64) void k_tyw(const float* __restrict__ emb,
                                            const int* __restrict__ off,
                                            const int* __restrict__ elist,
                                            const int* __restrict__ lc,
                                            const float* __restrict__ w,
                                            unsigned short* __restrict__ tyh,
                                            unsigned short* __restrict__ tyl) {
    int l = blockIdx.x;
    int lane = threadIdx.x;
    int d0 = lane * 2;
    if (l >= LCOM) {
        ushort2 z = {0, 0};
        *(ushort2*)(tyh + (size_t)l * 128 + d0) = z;
        *(ushort2*)(tyl + (size_t)l * 128 + d0) = z;
        return;
    }
    int row = lc[l];
    int s0 = off[row], s1 = off[row + 1];
    float2 acc = {0.f, 0.f};
    for (int i = s0; i < s1; i++) {
        int s = elist[i];
        float2 v = *(const float2*)(emb + (size_t)s * DIM + lane * 2);
        acc.x += v.x; acc.y += v.y;
    }
    float inv = 1.0f / (float)max(s1 - s0, 1);
    float2 e = *(const float2*)(emb + (size_t)row * DIM + lane * 2);
    float v0 = fmaxf(e.x + acc.x * inv, 0.f) * w[d0];
    float v1 = fmaxf(e.y + acc.y * inv, 0.f) * w[d0 + 1];
    unsigned short h0 = f2bf(v0), h1 = f2bf(v1);
    ushort2 hh = {h0, h1};
    ushort2 ll = {f2bf(v0 - bf2f(h0)), f2bf(v1 - bf2f(h1))};
    *(ushort2*)(tyh + (size_t)l * 128 + d0) = hh;
    *(ushort2*)(tyl + (size_t)l * 128 + d0) = ll;
}

// ---------------- rgcn aggregation: gather (fp32), unroll x2 ----------------
__global__ __launch_bounds__(256) void k_rgcn_gather(const float* __restrict__ x,
                                                     const int* __restrict__ off,
                                                     const int* __restrict__ elist,
                                                     const int* __restrict__ cnt,
                                                     const float* __restrict__ comp,
                                                     float* __restrict__ agg, int n) {
    int node = blockIdx.x * 4 + (threadIdx.x >> 6);
    int lane = threadIdx.x & 63;
    if (node >= n) return;
    int s0 = off[node], s1 = off[node + 1];
    const int* cb = cnt + node * NREL;
    float2 a0 = {0, 0}, a1 = {0, 0}, a2 = {0, 0}, a3 = {0, 0};
    int i = s0;
    for (; i + 1 < s1; i += 2) {
        int pa = elist[i], pb = elist[i + 1];
        int sa = pa >> 4, ta = pa & 15;
        int sb = pb >> 4, tb = pb & 15;
        float2 va = *(const float2*)(x + (size_t)sa * DIM + lane * 2);
        float2 vb = *(const float2*)(x + (size_t)sb * DIM + lane * 2);
        float na = 1.0f / fmaxf((float)cb[ta], 1.0f);
        float nb = 1.0f / fmaxf((float)cb[tb], 1.0f);
        float c;
        c = comp[ta * NB + 0] * na; a0.x = fmaf(c, va.x, a0.x); a0.y = fmaf(c, va.y, a0.y);
        c = comp[ta * NB + 1] * na; a1.x = fmaf(c, va.x, a1.x); a1.y = fmaf(c, va.y, a1.y);
        c = comp[ta * NB + 2] * na; a2.x = fmaf(c, va.x, a2.x); a2.y = fmaf(c, va.y, a2.y);
        c = comp[ta * NB + 3] * na; a3.x = fmaf(c, va.x, a3.x); a3.y = fmaf(c, va.y, a3.y);
        c = comp[tb * NB + 0] * nb; a0.x = fmaf(c, vb.x, a0.x); a0.y = fmaf(c, vb.y, a0.y);
        c = comp[tb * NB + 1] * nb; a1.x = fmaf(c, vb.x, a1.x); a1.y = fmaf(c, vb.y, a1.y);
        c = comp[tb * NB + 2] * nb; a2.x = fmaf(c, vb.x, a2.x); a2.y = fmaf(c, vb.y, a2.y);
        c = comp[tb * NB + 3] * nb; a3.x = fmaf(c, vb.x, a3.x); a3.y = fmaf(c, vb.y, a3.y);
    }
    if (i < s1) {
        int pa = elist[i];
        int sa = pa >> 4, ta = pa & 15;
        float2 va = *(const float2*)(x + (size_t)sa * DIM + lane * 2);
        float na = 1.0f / fmaxf((float)cb[ta], 1.0f);
        float c;
        c = comp[ta * NB + 0] * na; a0.x = fmaf(c, va.x, a0.x); a0.y = fmaf(c, va.y, a0.y);
        c = comp[ta * NB + 1] * na; a1.x = fmaf(c, va.x, a1.x); a1.y = fmaf(c, va.y, a1.y);
        c = comp[ta * NB + 2] * na; a2.x = fmaf(c, va.x, a2.x); a2.y = fmaf(c, va.y, a2.y);
        c = comp[ta * NB + 3] * na; a3.x = fmaf(c, va.x, a3.x); a3.y = fmaf(c, va.y, a3.y);
    }
    float* o = agg + (size_t)node * (NB * DIM) + lane * 2;
    *(float2*)(o + 0 * DIM) = a0;
    *(float2*)(o + 1 * DIM) = a1;
    *(float2*)(o + 2 * DIM) = a2;
    *(float2*)(o + 3 * DIM) = a3;
}

// ---------------- split-precision MFMA GEMM ----------------
#define LDSK 40
__global__ __launch_bounds__(256) void k_gemm(const float* __restrict__ x,
                                              const float* __restrict__ agg,
                                              const unsigned short* __restrict__ Wh,
                                              const unsigned short* __restrict__ Wl,
                                              const float* __restrict__ bias,
                                              float* __restrict__ out, int relu) {
    __shared__ __align__(16) short Ah[128 * LDSK];
    __shared__ __align__(16) short Al[128 * LDSK];
    __shared__ __align__(16) short Bh[128 * LDSK];
    __shared__ __align__(16) short Bl[128 * LDSK];
    int tid = threadIdx.x;
    int lane = tid & 63, wid = tid >> 6;
    int wave_m = wid >> 1, wave_n = wid & 1;
    int l15 = lane & 15, quad = lane >> 4;
    int row0 = blockIdx.x * 128;

    int srow = tid >> 1, skh = (tid & 1) * 16;

    f32x4 acc[4][4] = {};
    for (int k0 = 0; k0 < 640; k0 += 32) {
        {
            int rg = row0 + srow;
            float4 q0 = {0, 0, 0, 0}, q1 = q0, q2 = q0, q3 = q0;
            if (rg < N2) {
                const float* src = (k0 < 128) ? (x + (size_t)rg * 128 + k0 + skh)
                                              : (agg + (size_t)rg * 512 + (k0 - 128) + skh);
                q0 = *(const float4*)(src + 0);
                q1 = *(const float4*)(src + 4);
                q2 = *(const float4*)(src + 8);
                q3 = *(const float4*)(src + 12);
            }
            short8 h0, l0, h1, l1;
            split8(q0, q1, h0, l0);
            split8(q2, q3, h1, l1);
            *(short8*)(&Ah[srow * LDSK + skh]) = h0;
            *(short8*)(&Ah[srow * LDSK + skh + 8]) = h1;
            *(short8*)(&Al[srow * LDSK + skh]) = l0;
            *(short8*)(&Al[srow * LDSK + skh + 8]) = l1;
        }
        {
            const unsigned short* sh = Wh + (size_t)srow * 640 + k0 + skh;
            const unsigned short* sl = Wl + (size_t)srow * 640 + k0 + skh;
            *(short8*)(&Bh[srow * LDSK + skh]) = *(const short8*)(sh);
            *(short8*)(&Bh[srow * LDSK + skh + 8]) = *(const short8*)(sh + 8);
            *(short8*)(&Bl[srow * LDSK + skh]) = *(const short8*)(sl);
            *(short8*)(&Bl[srow * LDSK + skh + 8]) = *(const short8*)(sl + 8);
        }
        __syncthreads();
        short8 ah[4], al[4], bh[4], bl[4];
#pragma unroll
        for (int i = 0; i < 4; i++) {
            int ro = (wave_m * 64 + i * 16 + l15) * LDSK + quad * 8;
            ah[i] = *(const short8*)(&Ah[ro]);
            al[i] = *(const short8*)(&Al[ro]);
        }
#pragma unroll
        for (int j = 0; j < 4; j++) {
            int ro = (wave_n * 64 + j * 16 + l15) * LDSK + quad * 8;
            bh[j] = *(const short8*)(&Bh[ro]);
            bl[j] = *(const short8*)(&Bl[ro]);
        }
#pragma unroll
        for (int i = 0; i < 4; i++)
#pragma unroll
            for (int j = 0; j < 4; j++) {
                acc[i][j] = __builtin_amdgcn_mfma_f32_16x16x32_bf16(al[i], bh[j], acc[i][j], 0, 0, 0);
                acc[i][j] = __builtin_amdgcn_mfma_f32_16x16x32_bf16(ah[i], bl[j], acc[i][j], 0, 0, 0);
                acc[i][j] = __builtin_amdgcn_mfma_f32_16x16x32_bf16(ah[i], bh[j], acc[i][j], 0, 0, 0);
            }
        __syncthreads();
    }
#pragma unroll
    for (int j = 0; j < 4; j++) {
        int gcol = wave_n * 64 + j * 16 + l15;
        float bv = bias[gcol];
#pragma unroll
        for (int i = 0; i < 4; i++) {
            int grow_base = row0 + wave_m * 64 + i * 16 + quad * 4;
#pragma unroll
            for (int r = 0; r < 4; r++) {
                int grow = grow_base + r;
                if (grow >= N2) continue;
                float v = acc[i][j][r] + bv;
                if (relu) v = fmaxf(v, 0.f);
                out[(size_t)grow * 128 + gcol] = v;
            }
        }
    }
}

// ---------------- logits + softmax: MFMA, no LDS ----------------
// Block: 256 thr = 4 waves x 16 rows = 64 rows. N = 112 (7 tiles), K = 128 (4 steps x 3 passes).
// C layout: col = lane&15 (within tile), row = quad*4 + reg -> softmax = width-16 shfl butterfly.
__global__ __launch_bounds__(256) void k_logits(const float* __restrict__ h2,
                                                const unsigned short* __restrict__ tyh,
                                                const unsigned short* __restrict__ tyl,
                                                float* __restrict__ out, int M) {
    int wid = threadIdx.x >> 6, lane = threadIdx.x & 63;
    int l15 = lane & 15, quad = lane >> 4;
    int row0w = blockIdx.x * 64 + wid * 16;        // wave's first row
    int arow = min(row0w + l15, M - 1);            // A-frag row for this lane (clamped)
    f32x4 acc[7] = {};
#pragma unroll
    for (int k0 = 0; k0 < 128; k0 += 32) {
        const float* ap = h2 + (size_t)arow * 128 + k0 + quad * 8;
        float4 q0 = *(const float4*)(ap);
        float4 q1 = *(const float4*)(ap + 4);
        short8 ah, al;
        split8(q0, q1, ah, al);
#pragma unroll
        for (int j = 0; j < 7; j++) {
            size_t bo = (size_t)(j * 16 + l15) * 128 + k0 + quad * 8;
            short8 bh = *(const short8*)(tyh + bo);
            short8 bl = *(const short8*)(tyl + bo);
            acc[j] = __builtin_amdgcn_mfma_f32_16x16x32_bf16(al, bh, acc[j], 0, 0, 0);
            acc[j] = __builtin_amdgcn_mfma_f32_16x16x32_bf16(ah, bl, acc[j], 0, 0, 0);
            acc[j] = __builtin_amdgcn_mfma_f32_16x16x32_bf16(ah, bh, acc[j], 0, 0, 0);
        }
    }
    bool v6 = (l15 < LCOM - 96);  // tile 6 cols 96..111: valid iff l15 < 4
#pragma unroll
    for (int r = 0; r < 4; r++) {
        int grow = row0w + quad * 4 + r;
        float m = -INFINITY;
#pragma unroll
        for (int j = 0; j < 6; j++) m = fmaxf(m, acc[j][r]);
        if (v6) m = fmaxf(m, acc[6][r]);
        m = fmaxf(m, __shfl_xor(m, 8, 64));
        m = fmaxf(m, __shfl_xor(m, 4, 64));
        m = fmaxf(m, __shfl_xor(m, 2, 64));
        m = fmaxf(m, __shfl_xor(m, 1, 64));
        float e[7];
        float s = 0.f;
#pragma unroll
        for (int j = 0; j < 6; j++) { e[j] = __expf(acc[j][r] - m); s += e[j]; }
        e[6] = v6 ? __expf(acc[6][r] - m) : 0.f;
        s += e[6];
        s += __shfl_xor(s, 8, 64);
        s += __shfl_xor(s, 4, 64);
        s += __shfl_xor(s, 2, 64);
        s += __shfl_xor(s, 1, 64);
        float inv = 1.0f / s;
        if (grow < M) {
#pragma unroll
            for (int j = 0; j < 6; j++) out[(size_t)grow * LCOM + j * 16 + l15] = e[j] * inv;
            if (v6) out[(size_t)grow * LCOM + 96 + l15] = e[6] * inv;
        }
    }
}

extern "C" void kernel_launch(void* const* d_in, const int* in_sizes, int n_in,
                              void* d_out, int out_size, void* d_ws, size_t ws_size,
                              hipStream_t stream) {
    const int* ei2 = (const int*)d_in[0];
    const int* et2 = (const int*)d_in[1];
    const int* ei1 = (const int*)d_in[2];
    const int* lc = (const int*)d_in[3];
    const float* emb = (const float*)d_in[4];
    const float* basis1 = (const float*)d_in[5];
    const float* comp1 = (const float*)d_in[6];
    const float* root1 = (const float*)d_in[7];
    const float* bias1 = (const float*)d_in[8];
    const float* basis2 = (const float*)d_in[9];
    const float* comp2 = (const float*)d_in[10];
    const float* root2 = (const float*)d_in[11];
    const float* bias2 = (const float*)d_in[12];
    const float* wts = (const float*)d_in[13];
    float* out = (float*)d_out;
    int E2 = in_sizes[0] / 2, E1 = in_sizes[2] / 2;

    float* ws = (float*)d_ws;
    float* xg1 = ws;                       // 6,400,000 (50000x128; reused as h2)
    float* h1 = xg1 + 6400000;             // 6,400,000
    float* agg = h1 + 6400000;             // 25,600,000
    unsigned short* tyh = (unsigned short*)(agg + 25600000);  // 14,336
    unsigned short* tyl = tyh + LPAD * 128;                   // 14,336
    unsigned short* Wh1 = tyl + LPAD * 128;
    unsigned short* Wl1 = Wh1 + 81920;
    unsigned short* Wh2 = Wl1 + 81920;
    unsigned short* Wl2 = Wh2 + 81920;
    int* ipool = (int*)(Wl2 + 81920);
    int* deg1 = ipool;                     // 60,000
    int* off1 = deg1 + 60000;              // 60,001
    int* cur1 = off1 + 60001;              // 60,000
    int* elist1 = cur1 + 60000;            // 800,000
    int* cnt2 = elist1 + 800000;           // 800,000
    int* deg2 = cnt2 + 800000;             // 50,000
    int* off2 = deg2 + 50000;              // 50,001
    int* cur2 = off2 + 50001;              // 50,000
    int* elist2 = cur2 + 50000;            // 800,000
    int* bsum1 = elist2 + 800000;          // 64
    int* boff1 = bsum1 + 64;               // 64
    int* bsum2 = boff1 + 64;               // 64
    int* boff2 = bsum2 + 64;               // 64
    float* h2 = xg1;

    const int NB1 = (N1 + 1023) / 1024;    // 59
    const int NB2 = (N2 + 1023) / 1024;    // 49

    // ---- weight prep ----
    k_prep_w<<<(640 * 128 + 255) / 256, 256, 0, stream>>>(root1, basis1, Wh1, Wl1);
    k_prep_w<<<(640 * 128 + 255) / 256, 256, 0, stream>>>(root2, basis2, Wh2, Wl2);

    // ---- g1 CSR + concept layer (rows < 50000) + tyw ----
    hipMemsetAsync(deg1, 0, 60000 * sizeof(int), stream);
    k_hist_deg<<<(E1 + 255) / 256, 256, 0, stream>>>(ei1, deg1, E1);
    k_scan_p1<<<NB1, 256, 0, stream>>>(deg1, bsum1, N1);
    k_scan_p2<<<1, 64, 0, stream>>>(bsum1, boff1, off1, NB1, N1);
    k_scan_p3<<<NB1, 256, 0, stream>>>(deg1, boff1, off1, cur1, N1);
    k_csr_scatter1<<<(E1 + 255) / 256, 256, 0, stream>>>(ei1, cur1, elist1, E1);
    k_concept_gather<<<(N2 + 3) / 4, 256, 0, stream>>>(emb, off1, elist1, xg1, N2);
    k_tyw<<<LPAD, 64, 0, stream>>>(emb, off1, elist1, lc, wts, tyh, tyl);

    // ---- g2 CSR ----
    hipMemsetAsync(cnt2, 0, 800000 * sizeof(int), stream);
    k_hist_dt<<<(E2 + 255) / 256, 256, 0, stream>>>(ei2, et2, cnt2, E2);
    k_deg_from_cnt<<<(N2 + 255) / 256, 256, 0, stream>>>(cnt2, deg2, N2);
    k_scan_p1<<<NB2, 256, 0, stream>>>(deg2, bsum2, N2);
    k_scan_p2<<<1, 64, 0, stream>>>(bsum2, boff2, off2, NB2, N2);
    k_scan_p3<<<NB2, 256, 0, stream>>>(deg2, boff2, off2, cur2, N2);
    k_csr_scatter2<<<(E2 + 255) / 256, 256, 0, stream>>>(ei2, et2, cur2, elist2, E2);

    // ---- rgcn layer 1 ----
    k_rgcn_gather<<<(N2 + 3) / 4, 256, 0, stream>>>(xg1, off2, elist2, cnt2, comp1, agg, N2);
    k_gemm<<<(N2 + 127) / 128, 256, 0, stream>>>(xg1, agg, Wh1, Wl1, bias1, h1, 1);

    // ---- rgcn layer 2 ----
    k_rgcn_gather<<<(N2 + 3) / 4, 256, 0, stream>>>(h1, off2, elist2, cnt2, comp2, agg, N2);
    k_gemm<<<(N2 + 127) / 128, 256, 0, stream>>>(h1, agg, Wh2, Wl2, bias2, h2, 0);

    // ---- logits + softmax ----
    k_logits<<<(N2 + 63) / 64, 256, 0, stream>>>(h2, tyh, tyl, out, N2);
}

// Round 9
// 629.219 us; speedup vs baseline: 19.8176x; 1.0387x over previous
//
#include <hip/hip_runtime.h>
#include <hip/hip_bf16.h>
#include <math.h>

#define N1 60000
#define N2 50000
#define DIM 128
#define NREL 16
#define NB 4
#define LCOM 100
#define LPAD 112  // LCOM padded to 7x16 for MFMA N-tiles

typedef __attribute__((ext_vector_type(8))) short short8;
typedef __attribute__((ext_vector_type(4))) float f32x4;

__device__ __forceinline__ float bf2f(unsigned short u) {
    union { unsigned int i; float f; } c; c.i = ((unsigned int)u) << 16; return c.f;
}
__device__ __forceinline__ unsigned short f2bf(float f) {
    union { float f; unsigned int i; } c; c.f = f;
    unsigned int r = c.i + 0x7FFF + ((c.i >> 16) & 1);  // RNE
    return (unsigned short)(r >> 16);
}
__device__ __forceinline__ void split8(float4 a, float4 b, short8& h, short8& l) {
    float f[8] = {a.x, a.y, a.z, a.w, b.x, b.y, b.z, b.w};
#pragma unroll
    for (int j = 0; j < 8; j++) {
        unsigned short hh = f2bf(f[j]);
        h[j] = (short)hh;
        l[j] = (short)f2bf(f[j] - bf2f(hh));
    }
}

// ---------------- weight prep: W=[root;basis_flat] (640x128) -> Wt_hi/lo[n*640+k] ----------------
__global__ void k_prep_w(const float* __restrict__ root, const float* __restrict__ basis,
                         unsigned short* __restrict__ Wh, unsigned short* __restrict__ Wl) {
    int t = blockIdx.x * blockDim.x + threadIdx.x;
    if (t >= 640 * 128) return;
    int k = t >> 7, n = t & 127;
    float v = (k < 128) ? root[k * 128 + n] : basis[(k - 128) * 128 + n];
    unsigned short h = f2bf(v);
    Wh[n * 640 + k] = h;
    Wl[n * 640 + k] = f2bf(v - bf2f(h));
}

// ---------------- histograms ----------------
__global__ void k_hist_deg(const int* __restrict__ ei, int* __restrict__ deg, int E) {
    int e = blockIdx.x * blockDim.x + threadIdx.x;
    if (e >= E) return;
    atomicAdd(deg + ei[E + e], 1);
}

__global__ void k_hist_dt(const int* __restrict__ ei, const int* __restrict__ et,
                          int* __restrict__ cnt, int E) {
    int e = blockIdx.x * blockDim.x + threadIdx.x;
    if (e >= E) return;
    atomicAdd(cnt + ei[E + e] * NREL + et[e], 1);
}

__global__ void k_deg_from_cnt(const int* __restrict__ cnt, int* __restrict__ deg, int n) {
    int i = blockIdx.x * blockDim.x + threadIdx.x;
    if (i >= n) return;
    int s = 0;
#pragma unroll
    for (int t = 0; t < NREL; t++) s += cnt[i * NREL + t];
    deg[i] = s;
}

// ---------------- hierarchical exclusive scan (3 phases) ----------------
__global__ __launch_bounds__(256) void k_scan_p1(const int* __restrict__ in,
                                                 int* __restrict__ bsum, int n) {
    __shared__ int red[256];
    int base = blockIdx.x * 1024;
    int tid = threadIdx.x;
    int s = 0;
#pragma unroll
    for (int j = 0; j < 4; j++) {
        int i = base + tid * 4 + j;
        if (i < n) s += in[i];
    }
    red[tid] = s;
    __syncthreads();
    for (int d = 128; d; d >>= 1) {
        if (tid < d) red[tid] += red[tid + d];
        __syncthreads();
    }
    if (tid == 0) bsum[blockIdx.x] = red[0];
}

__global__ __launch_bounds__(64) void k_scan_p2(const int* __restrict__ bsum,
                                                int* __restrict__ boff,
                                                int* __restrict__ off, int nb, int n) {
    __shared__ int s[64];
    int tid = threadIdx.x;
    int v = (tid < nb) ? bsum[tid] : 0;
    s[tid] = v;
    __syncthreads();
    for (int d = 1; d < 64; d <<= 1) {
        int t = (tid >= d) ? s[tid - d] : 0;
        __syncthreads();
        s[tid] += t;
        __syncthreads();
    }
    if (tid < nb) boff[tid] = s[tid] - v;
    if (tid == 63) off[n] = s[63];
}

__global__ __launch_bounds__(256) void k_scan_p3(const int* __restrict__ in,
                                                 const int* __restrict__ boff,
                                                 int* __restrict__ off,
                                                 int* __restrict__ cur, int n) {
    __shared__ int red[256];
    int base = blockIdx.x * 1024;
    int tid = threadIdx.x;
    int v[4];
    int s = 0;
#pragma unroll
    for (int j = 0; j < 4; j++) {
        int i = base + tid * 4 + j;
        v[j] = (i < n) ? in[i] : 0;
        s += v[j];
    }
    red[tid] = s;
    __syncthreads();
    for (int d = 1; d < 256; d <<= 1) {
        int t = (tid >= d) ? red[tid - d] : 0;
        __syncthreads();
        red[tid] += t;
        __syncthreads();
    }
    int run = boff[blockIdx.x] + red[tid] - s;
#pragma unroll
    for (int j = 0; j < 4; j++) {
        int i = base + tid * 4 + j;
        if (i < n) {
            off[i] = run; cur[i] = run;
            run += v[j];
        }
    }
}

// ---------------- CSR scatter ----------------
__global__ void k_csr_scatter1(const int* __restrict__ ei, int* __restrict__ cur,
                               int* __restrict__ elist, int E) {
    int e = blockIdx.x * blockDim.x + threadIdx.x;
    if (e >= E) return;
    int pos = atomicAdd(cur + ei[E + e], 1);
    elist[pos] = ei[e];
}

// also writes per-slot norm 1/max(cnt[dst,t],1) (layer-invariant)
__global__ void k_csr_scatter2(const int* __restrict__ ei, const int* __restrict__ et,
                               const int* __restrict__ cnt, int* __restrict__ cur,
                               int* __restrict__ elist, float* __restrict__ nrmv, int E) {
    int e = blockIdx.x * blockDim.x + threadIdx.x;
    if (e >= E) return;
    int dst = ei[E + e], t = et[e];
    int pos = atomicAdd(cur + dst, 1);
    elist[pos] = (ei[e] << 4) | t;
    nrmv[pos] = 1.0f / fmaxf((float)cnt[dst * NREL + t], 1.0f);
}

// ---------------- concept layer: gather-mean (fp32), 2 edges/wave, float4/lane ----------------
__global__ __launch_bounds__(256) void k_concept_gather(const float* __restrict__ emb,
                                                        const int* __restrict__ off,
                                                        const int* __restrict__ elist,
                                                        float* __restrict__ xg1, int n) {
    int node = blockIdx.x * 4 + (threadIdx.x >> 6);
    int lane = threadIdx.x & 63;
    if (node >= n) return;
    int half = lane >> 5, d4 = (lane & 31) * 4;
    int s0 = off[node], s1 = off[node + 1];
    float4 acc = {0.f, 0.f, 0.f, 0.f};
    int i = s0;
    for (; i + 4 <= s1; i += 4) {
        int sa = elist[i + half];
        int sb = elist[i + 2 + half];
        float4 va = *(const float4*)(emb + (size_t)sa * DIM + d4);
        float4 vb = *(const float4*)(emb + (size_t)sb * DIM + d4);
        acc.x += va.x + vb.x; acc.y += va.y + vb.y;
        acc.z += va.z + vb.z; acc.w += va.w + vb.w;
    }
    for (; i < s1; i += 2) {
        int e = i + half;
        bool ok = e < s1;
        int s = elist[ok ? e : i];
        float4 v = *(const float4*)(emb + (size_t)s * DIM + d4);
        if (ok) { acc.x += v.x; acc.y += v.y; acc.z += v.z; acc.w += v.w; }
    }
    acc.x += __shfl_xor(acc.x, 32, 64);
    acc.y += __shfl_xor(acc.y, 32, 64);
    acc.z += __shfl_xor(acc.z, 32, 64);
    acc.w += __shfl_xor(acc.w, 32, 64);
    if (half == 0) {
        float inv = 1.0f / (float)max(s1 - s0, 1);
        float4 e = *(const float4*)(emb + (size_t)node * DIM + d4);
        float4 o = {fmaxf(e.x + acc.x * inv, 0.f), fmaxf(e.y + acc.y * inv, 0.f),
                    fmaxf(e.z + acc.z * inv, 0.f), fmaxf(e.w + acc.w * inv, 0.f)};
        *(float4*)(xg1 + (size_t)node * DIM + d4) = o;
    }
}

// ---------------- tyw: concept row lc[l] on the fly -> split bf16 hi/lo, [n][k] layout ----------------
__global__ __launch_bounds__(64) void k_tyw(const float* __restrict__ emb,
                                            const int* __restrict__ off,
                                            const int* __restrict__ elist,
                                            const int* __restrict__ lc,
                                            const float* __restrict__ w,
                                            unsigned short* __restrict__ tyh,
                                            unsigned short* __restrict__ tyl) {
    int l = blockIdx.x;
    int lane = threadIdx.x;
    int d0 = lane * 2;
    if (l >= LCOM) {
        ushort2 z = {0, 0};
        *(ushort2*)(tyh + (size_t)l * 128 + d0) = z;
        *(ushort2*)(tyl + (size_t)l * 128 + d0) = z;
        return;
    }
    int row = lc[l];
    int s0 = off[row], s1 = off[row + 1];
    float2 acc = {0.f, 0.f};
    for (int i = s0; i < s1; i++) {
        int s = elist[i];
        float2 v = *(const float2*)(emb + (size_t)s * DIM + lane * 2);
        acc.x += v.x; acc.y += v.y;
    }
    float inv = 1.0f / (float)max(s1 - s0, 1);
    float2 e = *(const float2*)(emb + (size_t)row * DIM + lane * 2);
    float v0 = fmaxf(e.x + acc.x * inv, 0.f) * w[d0];
    float v1 = fmaxf(e.y + acc.y * inv, 0.f) * w[d0 + 1];
    unsigned short h0 = f2bf(v0), h1 = f2bf(v1);
    ushort2 hh = {h0, h1};
    ushort2 ll = {f2bf(v0 - bf2f(h0)), f2bf(v1 - bf2f(h1))};
    *(ushort2*)(tyh + (size_t)l * 128 + d0) = hh;
    *(ushort2*)(tyl + (size_t)l * 128 + d0) = ll;
}

// ---------------- rgcn aggregation: 2 edges/wave, float4/lane, LDS comp, precomputed nrm ----------------
__global__ __launch_bounds__(256) void k_rgcn_gather(const float* __restrict__ x,
                                                     const int* __restrict__ off,
                                                     const int* __restrict__ elist,
                                                     const float* __restrict__ nrmv,
                                                     const float* __restrict__ comp,
                                                     float* __restrict__ agg, int n) {
    __shared__ float scomp[NREL * NB];
    if (threadIdx.x < NREL * NB) scomp[threadIdx.x] = comp[threadIdx.x];
    __syncthreads();
    int node = blockIdx.x * 4 + (threadIdx.x >> 6);
    int lane = threadIdx.x & 63;
    if (node >= n) return;
    int half = lane >> 5, d4 = (lane & 31) * 4;
    int s0 = off[node], s1 = off[node + 1];
    float4 a0 = {0, 0, 0, 0}, a1 = a0, a2 = a0, a3 = a0;
    int i = s0;
#define RG_EDGE(E_IDX, NRM)                                                    \
    {                                                                          \
        int p = elist[E_IDX];                                                  \
        float nr = (NRM);                                                      \
        int s = p >> 4, t = p & 15;                                            \
        float4 cf = *(const float4*)(scomp + t * 4);                           \
        float4 v = *(const float4*)(x + (size_t)s * DIM + d4);                 \
        float c0 = cf.x * nr, c1 = cf.y * nr, c2 = cf.z * nr, c3 = cf.w * nr;  \
        a0.x = fmaf(c0, v.x, a0.x); a0.y = fmaf(c0, v.y, a0.y);                \
        a0.z = fmaf(c0, v.z, a0.z); a0.w = fmaf(c0, v.w, a0.w);                \
        a1.x = fmaf(c1, v.x, a1.x); a1.y = fmaf(c1, v.y, a1.y);                \
        a1.z = fmaf(c1, v.z, a1.z); a1.w = fmaf(c1, v.w, a1.w);                \
        a2.x = fmaf(c2, v.x, a2.x); a2.y = fmaf(c2, v.y, a2.y);                \
        a2.z = fmaf(c2, v.z, a2.z); a2.w = fmaf(c2, v.w, a2.w);                \
        a3.x = fmaf(c3, v.x, a3.x); a3.y = fmaf(c3, v.y, a3.y);                \
        a3.z = fmaf(c3, v.z, a3.z); a3.w = fmaf(c3, v.w, a3.w);                \
    }
    for (; i + 4 <= s1; i += 4) {
        RG_EDGE(i + half, nrmv[i + half]);
        RG_EDGE(i + 2 + half, nrmv[i + 2 + half]);
    }
    for (; i < s1; i += 2) {
        int e = i + half;
        bool ok = e < s1;
        int ei_ = ok ? e : i;
        RG_EDGE(ei_, ok ? nrmv[ei_] : 0.0f);
    }
#undef RG_EDGE
    a0.x += __shfl_xor(a0.x, 32, 64); a0.y += __shfl_xor(a0.y, 32, 64);
    a0.z += __shfl_xor(a0.z, 32, 64); a0.w += __shfl_xor(a0.w, 32, 64);
    a1.x += __shfl_xor(a1.x, 32, 64); a1.y += __shfl_xor(a1.y, 32, 64);
    a1.z += __shfl_xor(a1.z, 32, 64); a1.w += __shfl_xor(a1.w, 32, 64);
    a2.x += __shfl_xor(a2.x, 32, 64); a2.y += __shfl_xor(a2.y, 32, 64);
    a2.z += __shfl_xor(a2.z, 32, 64); a2.w += __shfl_xor(a2.w, 32, 64);
    a3.x += __shfl_xor(a3.x, 32, 64); a3.y += __shfl_xor(a3.y, 32, 64);
    a3.z += __shfl_xor(a3.z, 32, 64); a3.w += __shfl_xor(a3.w, 32, 64);
    if (half == 0) {
        float* o = agg + (size_t)node * (NB * DIM) + d4;
        *(float4*)(o + 0 * DIM) = a0;
        *(float4*)(o + 1 * DIM) = a1;
        *(float4*)(o + 2 * DIM) = a2;
        *(float4*)(o + 3 * DIM) = a3;
    }
}

// ---------------- split-precision MFMA GEMM ----------------
#define LDSK 40
__global__ __launch_bounds__(256) void k_gemm(const float* __restrict__ x,
                                              const float* __restrict__ agg,
                                              const unsigned short* __restrict__ Wh,
                                              const unsigned short* __restrict__ Wl,
                                              const float* __restrict__ bias,
                                              float* __restrict__ out, int relu) {
    __shared__ __align__(16) short Ah[128 * LDSK];
    __shared__ __align__(16) short Al[128 * LDSK];
    __shared__ __align__(16) short Bh[128 * LDSK];
    __shared__ __align__(16) short Bl[128 * LDSK];
    int tid = threadIdx.x;
    int lane = tid & 63, wid = tid >> 6;
    int wave_m = wid >> 1, wave_n = wid & 1;
    int l15 = lane & 15, quad = lane >> 4;
    int row0 = blockIdx.x * 128;

    int srow = tid >> 1, skh = (tid & 1) * 16;

    f32x4 acc[4][4] = {};
    for (int k0 = 0; k0 < 640; k0 += 32) {
        {
            int rg = row0 + srow;
            float4 q0 = {0, 0, 0, 0}, q1 = q0, q2 = q0, q3 = q0;
            if (rg < N2) {
                const float* src = (k0 < 128) ? (x + (size_t)rg * 128 + k0 + skh)
                                              : (agg + (size_t)rg * 512 + (k0 - 128) + skh);
                q0 = *(const float4*)(src + 0);
                q1 = *(const float4*)(src + 4);
                q2 = *(const float4*)(src + 8);
                q3 = *(const float4*)(src + 12);
            }
            short8 h0, l0, h1, l1;
            split8(q0, q1, h0, l0);
            split8(q2, q3, h1, l1);
            *(short8*)(&Ah[srow * LDSK + skh]) = h0;
            *(short8*)(&Ah[srow * LDSK + skh + 8]) = h1;
            *(short8*)(&Al[srow * LDSK + skh]) = l0;
            *(short8*)(&Al[srow * LDSK + skh + 8]) = l1;
        }
        {
            const unsigned short* sh = Wh + (size_t)srow * 640 + k0 + skh;
            const unsigned short* sl = Wl + (size_t)srow * 640 + k0 + skh;
            *(short8*)(&Bh[srow * LDSK + skh]) = *(const short8*)(sh);
            *(short8*)(&Bh[srow * LDSK + skh + 8]) = *(const short8*)(sh + 8);
            *(short8*)(&Bl[srow * LDSK + skh]) = *(const short8*)(sl);
            *(short8*)(&Bl[srow * LDSK + skh + 8]) = *(const short8*)(sl + 8);
        }
        __syncthreads();
        short8 ah[4], al[4], bh[4], bl[4];
#pragma unroll
        for (int i = 0; i < 4; i++) {
            int ro = (wave_m * 64 + i * 16 + l15) * LDSK + quad * 8;
            ah[i] = *(const short8*)(&Ah[ro]);
            al[i] = *(const short8*)(&Al[ro]);
        }
#pragma unroll
        for (int j = 0; j < 4; j++) {
            int ro = (wave_n * 64 + j * 16 + l15) * LDSK + quad * 8;
            bh[j] = *(const short8*)(&Bh[ro]);
            bl[j] = *(const short8*)(&Bl[ro]);
        }
#pragma unroll
        for (int i = 0; i < 4; i++)
#pragma unroll
            for (int j = 0; j < 4; j++) {
                acc[i][j] = __builtin_amdgcn_mfma_f32_16x16x32_bf16(al[i], bh[j], acc[i][j], 0, 0, 0);
                acc[i][j] = __builtin_amdgcn_mfma_f32_16x16x32_bf16(ah[i], bl[j], acc[i][j], 0, 0, 0);
                acc[i][j] = __builtin_amdgcn_mfma_f32_16x16x32_bf16(ah[i], bh[j], acc[i][j], 0, 0, 0);
            }
        __syncthreads();
    }
#pragma unroll
    for (int j = 0; j < 4; j++) {
        int gcol = wave_n * 64 + j * 16 + l15;
        float bv = bias[gcol];
#pragma unroll
        for (int i = 0; i < 4; i++) {
            int grow_base = row0 + wave_m * 64 + i * 16 + quad * 4;
#pragma unroll
            for (int r = 0; r < 4; r++) {
                int grow = grow_base + r;
                if (grow >= N2) continue;
                float v = acc[i][j][r] + bv;
                if (relu) v = fmaxf(v, 0.f);
                out[(size_t)grow * 128 + gcol] = v;
            }
        }
    }
}

// ---------------- logits + softmax: MFMA, no LDS ----------------
__global__ __launch_bounds__(256) void k_logits(const float* __restrict__ h2,
                                                const unsigned short* __restrict__ tyh,
                                                const unsigned short* __restrict__ tyl,
                                                float* __restrict__ out, int M) {
    int wid = threadIdx.x >> 6, lane = threadIdx.x & 63;
    int l15 = lane & 15, quad = lane >> 4;
    int row0w = blockIdx.x * 64 + wid * 16;
    int arow = min(row0w + l15, M - 1);
    f32x4 acc[7] = {};
#pragma unroll
    for (int k0 = 0; k0 < 128; k0 += 32) {
        const float* ap = h2 + (size_t)arow * 128 + k0 + quad * 8;
        float4 q0 = *(const float4*)(ap);
        float4 q1 = *(const float4*)(ap + 4);
        short8 ah, al;
        split8(q0, q1, ah, al);
#pragma unroll
        for (int j = 0; j < 7; j++) {
            size_t bo = (size_t)(j * 16 + l15) * 128 + k0 + quad * 8;
            short8 bh = *(const short8*)(tyh + bo);
            short8 bl = *(const short8*)(tyl + bo);
            acc[j] = __builtin_amdgcn_mfma_f32_16x16x32_bf16(al, bh, acc[j], 0, 0, 0);
            acc[j] = __builtin_amdgcn_mfma_f32_16x16x32_bf16(ah, bl, acc[j], 0, 0, 0);
            acc[j] = __builtin_amdgcn_mfma_f32_16x16x32_bf16(ah, bh, acc[j], 0, 0, 0);
        }
    }
    bool v6 = (l15 < LCOM - 96);
#pragma unroll
    for (int r = 0; r < 4; r++) {
        int grow = row0w + quad * 4 + r;
        float m = -INFINITY;
#pragma unroll
        for (int j = 0; j < 6; j++) m = fmaxf(m, acc[j][r]);
        if (v6) m = fmaxf(m, acc[6][r]);
        m = fmaxf(m, __shfl_xor(m, 8, 64));
        m = fmaxf(m, __shfl_xor(m, 4, 64));
        m = fmaxf(m, __shfl_xor(m, 2, 64));
        m = fmaxf(m, __shfl_xor(m, 1, 64));
        float e[7];
        float s = 0.f;
#pragma unroll
        for (int j = 0; j < 6; j++) { e[j] = __expf(acc[j][r] - m); s += e[j]; }
        e[6] = v6 ? __expf(acc[6][r] - m) : 0.f;
        s += e[6];
        s += __shfl_xor(s, 8, 64);
        s += __shfl_xor(s, 4, 64);
        s += __shfl_xor(s, 2, 64);
        s += __shfl_xor(s, 1, 64);
        float inv = 1.0f / s;
        if (grow < M) {
#pragma unroll
            for (int j = 0; j < 6; j++) out[(size_t)grow * LCOM + j * 16 + l15] = e[j] * inv;
            if (v6) out[(size_t)grow * LCOM + 96 + l15] = e[6] * inv;
        }
    }
}

extern "C" void kernel_launch(void* const* d_in, const int* in_sizes, int n_in,
                              void* d_out, int out_size, void* d_ws, size_t ws_size,
                              hipStream_t stream) {
    const int* ei2 = (const int*)d_in[0];
    const int* et2 = (const int*)d_in[1];
    const int* ei1 = (const int*)d_in[2];
    const int* lc = (const int*)d_in[3];
    const float* emb = (const float*)d_in[4];
    const float* basis1 = (const float*)d_in[5];
    const float* comp1 = (const float*)d_in[6];
    const float* root1 = (const float*)d_in[7];
    const float* bias1 = (const float*)d_in[8];
    const float* basis2 = (const float*)d_in[9];
    const float* comp2 = (const float*)d_in[10];
    const float* root2 = (const float*)d_in[11];
    const float* bias2 = (const float*)d_in[12];
    const float* wts = (const float*)d_in[13];
    float* out = (float*)d_out;
    int E2 = in_sizes[0] / 2, E1 = in_sizes[2] / 2;

    float* ws = (float*)d_ws;
    float* xg1 = ws;                       // 6,400,000 (50000x128; reused as h2)
    float* h1 = xg1 + 6400000;             // 6,400,000
    float* agg = h1 + 6400000;             // 25,600,000
    float* nrmv = agg + 25600000;          // 800,000
    unsigned short* tyh = (unsigned short*)(nrmv + 800000);   // 14,336
    unsigned short* tyl = tyh + LPAD * 128;                   // 14,336
    unsigned short* Wh1 = tyl + LPAD * 128;
    unsigned short* Wl1 = Wh1 + 81920;
    unsigned short* Wh2 = Wl1 + 81920;
    unsigned short* Wl2 = Wh2 + 81920;
    int* ipool = (int*)(Wl2 + 81920);
    int* deg1 = ipool;                     // 60,000
    int* off1 = deg1 + 60000;              // 60,001
    int* cur1 = off1 + 60001;              // 60,000
    int* elist1 = cur1 + 60000;            // 800,000
    int* cnt2 = elist1 + 800000;           // 800,000
    int* deg2 = cnt2 + 800000;             // 50,000
    int* off2 = deg2 + 50000;              // 50,001
    int* cur2 = off2 + 50001;              // 50,000
    int* elist2 = cur2 + 50000;            // 800,000
    int* bsum1 = elist2 + 800000;          // 64
    int* boff1 = bsum1 + 64;               // 64
    int* bsum2 = boff1 + 64;               // 64
    int* boff2 = bsum2 + 64;               // 64
    float* h2 = xg1;

    const int NB1 = (N1 + 1023) / 1024;    // 59
    const int NB2 = (N2 + 1023) / 1024;    // 49

    // ---- weight prep ----
    k_prep_w<<<(640 * 128 + 255) / 256, 256, 0, stream>>>(root1, basis1, Wh1, Wl1);
    k_prep_w<<<(640 * 128 + 255) / 256, 256, 0, stream>>>(root2, basis2, Wh2, Wl2);

    // ---- g1 CSR + concept layer (rows < 50000) + tyw ----
    hipMemsetAsync(deg1, 0, 60000 * sizeof(int), stream);
    k_hist_deg<<<(E1 + 255) / 256, 256, 0, stream>>>(ei1, deg1, E1);
    k_scan_p1<<<NB1, 256, 0, stream>>>(deg1, bsum1, N1);
    k_scan_p2<<<1, 64, 0, stream>>>(bsum1, boff1, off1, NB1, N1);
    k_scan_p3<<<NB1, 256, 0, stream>>>(deg1, boff1, off1, cur1, N1);
    k_csr_scatter1<<<(E1 + 255) / 256, 256, 0, stream>>>(ei1, cur1, elist1, E1);
    k_concept_gather<<<(N2 + 3) / 4, 256, 0, stream>>>(emb, off1, elist1, xg1, N2);
    k_tyw<<<LPAD, 64, 0, stream>>>(emb, off1, elist1, lc, wts, tyh, tyl);

    // ---- g2 CSR ----
    hipMemsetAsync(cnt2, 0, 800000 * sizeof(int), stream);
    k_hist_dt<<<(E2 + 255) / 256, 256, 0, stream>>>(ei2, et2, cnt2, E2);
    k_deg_from_cnt<<<(N2 + 255) / 256, 256, 0, stream>>>(cnt2, deg2, N2);
    k_scan_p1<<<NB2, 256, 0, stream>>>(deg2, bsum2, N2);
    k_scan_p2<<<1, 64, 0, stream>>>(bsum2, boff2, off2, NB2, N2);
    k_scan_p3<<<NB2, 256, 0, stream>>>(deg2, boff2, off2, cur2, N2);
    k_csr_scatter2<<<(E2 + 255) / 256, 256, 0, stream>>>(ei2, et2, cnt2, cur2, elist2, nrmv, E2);

    // ---- rgcn layer 1 ----
    k_rgcn_gather<<<(N2 + 3) / 4, 256, 0, stream>>>(xg1, off2, elist2, nrmv, comp1, agg, N2);
    k_gemm<<<(N2 + 127) / 128, 256, 0, stream>>>(xg1, agg, Wh1, Wl1, bias1, h1, 1);

    // ---- rgcn layer 2 ----
    k_rgcn_gather<<<(N2 + 3) / 4, 256, 0, stream>>>(h1, off2, elist2, nrmv, comp2, agg, N2);
    k_gemm<<<(N2 + 127) / 128, 256, 0, stream>>>(h1, agg, Wh2, Wl2, bias2, h2, 0);

    // ---- logits + softmax ----
    k_logits<<<(N2 + 63) / 64, 256, 0, stream>>>(h2, tyh, tyl, out, N2);
}

// Round 10
// 597.425 us; speedup vs baseline: 20.8722x; 1.0532x over previous
//
#include <hip/hip_runtime.h>
#include <hip/hip_bf16.h>
#include <math.h>

#define N1 60000
#define N2 50000
#define DIM 128
#define NREL 16
#define NB 4
#define LCOM 100
#define LPAD 112  // LCOM padded to 7x16 for MFMA N-tiles

typedef __attribute__((ext_vector_type(8))) short short8;
typedef __attribute__((ext_vector_type(4))) float f32x4;
typedef __attribute__((ext_vector_type(4))) _Float16 half4;

__device__ __forceinline__ float bf2f(unsigned short u) {
    union { unsigned int i; float f; } c; c.i = ((unsigned int)u) << 16; return c.f;
}
__device__ __forceinline__ unsigned short f2bf(float f) {
    union { float f; unsigned int i; } c; c.f = f;
    unsigned int r = c.i + 0x7FFF + ((c.i >> 16) & 1);  // RNE
    return (unsigned short)(r >> 16);
}
__device__ __forceinline__ void split8(float4 a, float4 b, short8& h, short8& l) {
    float f[8] = {a.x, a.y, a.z, a.w, b.x, b.y, b.z, b.w};
#pragma unroll
    for (int j = 0; j < 8; j++) {
        unsigned short hh = f2bf(f[j]);
        h[j] = (short)hh;
        l[j] = (short)f2bf(f[j] - bf2f(hh));
    }
}

// ---------------- emb fp32 -> fp16 shadow ----------------
__global__ void k_cast_emb(const float* __restrict__ emb, _Float16* __restrict__ embh, int n4) {
    int i = blockIdx.x * blockDim.x + threadIdx.x;
    if (i >= n4) return;
    float4 v = ((const float4*)emb)[i];
    half4 o = {(_Float16)v.x, (_Float16)v.y, (_Float16)v.z, (_Float16)v.w};
    ((half4*)embh)[i] = o;
}

// ---------------- weight prep (both layers in one launch) ----------------
__global__ void k_prep_w2(const float* __restrict__ root1, const float* __restrict__ basis1,
                          unsigned short* __restrict__ Wh1, unsigned short* __restrict__ Wl1,
                          const float* __restrict__ root2, const float* __restrict__ basis2,
                          unsigned short* __restrict__ Wh2, unsigned short* __restrict__ Wl2) {
    int t = blockIdx.x * blockDim.x + threadIdx.x;
    if (t >= 2 * 640 * 128) return;
    int which = t >= 640 * 128;
    int tt = which ? t - 640 * 128 : t;
    const float* root = which ? root2 : root1;
    const float* basis = which ? basis2 : basis1;
    unsigned short* Wh = which ? Wh2 : Wh1;
    unsigned short* Wl = which ? Wl2 : Wl1;
    int k = tt >> 7, n = tt & 127;
    float v = (k < 128) ? root[k * 128 + n] : basis[(k - 128) * 128 + n];
    unsigned short h = f2bf(v);
    Wh[n * 640 + k] = h;
    Wl[n * 640 + k] = f2bf(v - bf2f(h));
}

// ---------------- both in-degree histograms in one launch ----------------
__global__ void k_hist_both(const int* __restrict__ ei1, int E1, int* __restrict__ deg1,
                            const int* __restrict__ ei2, int E2, int* __restrict__ deg2) {
    int g = blockIdx.x * blockDim.x + threadIdx.x;
    if (g < E1) atomicAdd(deg1 + ei1[E1 + g], 1);
    if (g < E2) atomicAdd(deg2 + ei2[E2 + g], 1);
}

// ---------------- merged hierarchical scan (two arrays per phase) ----------------
__global__ __launch_bounds__(256) void k_scan_p1m(const int* __restrict__ inA, int nA, int nbA,
                                                  int* __restrict__ bsumA,
                                                  const int* __restrict__ inB, int nB,
                                                  int* __restrict__ bsumB) {
    __shared__ int red[256];
    const int* in; int n; int* bsum; int b;
    if ((int)blockIdx.x < nbA) { in = inA; n = nA; bsum = bsumA; b = blockIdx.x; }
    else { in = inB; n = nB; bsum = bsumB; b = blockIdx.x - nbA; }
    int base = b * 1024;
    int tid = threadIdx.x;
    int s = 0;
#pragma unroll
    for (int j = 0; j < 4; j++) {
        int i = base + tid * 4 + j;
        if (i < n) s += in[i];
    }
    red[tid] = s;
    __syncthreads();
    for (int d = 128; d; d >>= 1) {
        if (tid < d) red[tid] += red[tid + d];
        __syncthreads();
    }
    if (tid == 0) bsum[b] = red[0];
}

__global__ __launch_bounds__(64) void k_scan_p2m(const int* __restrict__ bsumA, int* __restrict__ boffA,
                                                 int* __restrict__ offA, int nbA, int nA,
                                                 const int* __restrict__ bsumB, int* __restrict__ boffB,
                                                 int* __restrict__ offB, int nbB, int nB) {
    __shared__ int s[64];
    const int* bsum; int* boff; int* off; int nb; int n;
    if (blockIdx.x == 0) { bsum = bsumA; boff = boffA; off = offA; nb = nbA; n = nA; }
    else { bsum = bsumB; boff = boffB; off = offB; nb = nbB; n = nB; }
    int tid = threadIdx.x;
    int v = (tid < nb) ? bsum[tid] : 0;
    s[tid] = v;
    __syncthreads();
    for (int d = 1; d < 64; d <<= 1) {
        int t = (tid >= d) ? s[tid - d] : 0;
        __syncthreads();
        s[tid] += t;
        __syncthreads();
    }
    if (tid < nb) boff[tid] = s[tid] - v;
    if (tid == 63) off[n] = s[63];
}

__global__ __launch_bounds__(256) void k_scan_p3m(const int* __restrict__ inA, const int* __restrict__ boffA,
                                                  int* __restrict__ offA, int* __restrict__ curA,
                                                  int nA, int nbA,
                                                  const int* __restrict__ inB, const int* __restrict__ boffB,
                                                  int* __restrict__ offB, int* __restrict__ curB, int nB) {
    __shared__ int red[256];
    const int* in; const int* boff; int* off; int* cur; int n; int b;
    if ((int)blockIdx.x < nbA) { in = inA; boff = boffA; off = offA; cur = curA; n = nA; b = blockIdx.x; }
    else { in = inB; boff = boffB; off = offB; cur = curB; n = nB; b = blockIdx.x - nbA; }
    int base = b * 1024;
    int tid = threadIdx.x;
    int v[4];
    int s = 0;
#pragma unroll
    for (int j = 0; j < 4; j++) {
        int i = base + tid * 4 + j;
        v[j] = (i < n) ? in[i] : 0;
        s += v[j];
    }
    red[tid] = s;
    __syncthreads();
    for (int d = 1; d < 256; d <<= 1) {
        int t = (tid >= d) ? red[tid - d] : 0;
        __syncthreads();
        red[tid] += t;
        __syncthreads();
    }
    int run = boff[b] + red[tid] - s;
#pragma unroll
    for (int j = 0; j < 4; j++) {
        int i = base + tid * 4 + j;
        if (i < n) {
            off[i] = run; cur[i] = run;
            run += v[j];
        }
    }
}

// ---------------- both CSR scatters in one launch ----------------
__global__ void k_scat_both(const int* __restrict__ ei1, int E1, int* __restrict__ cur1,
                            int* __restrict__ elist1,
                            const int* __restrict__ ei2, const int* __restrict__ et2, int E2,
                            int* __restrict__ cur2, int* __restrict__ elist2) {
    int g = blockIdx.x * blockDim.x + threadIdx.x;
    if (g < E1) {
        int pos = atomicAdd(cur1 + ei1[E1 + g], 1);
        elist1[pos] = ei1[g];
    }
    if (g < E2) {
        int pos = atomicAdd(cur2 + ei2[E2 + g], 1);
        elist2[pos] = (ei2[g] << 4) | et2[g];
    }
}

// ---------------- per-node type counts -> packed {elist, nrm} (one thread per node) ----------------
__global__ void k_nrm_pack(const int* __restrict__ off, const int* __restrict__ elist,
                           int2* __restrict__ epack, int n) {
    int node = blockIdx.x * blockDim.x + threadIdx.x;
    if (node >= n) return;
    int s0 = off[node], s1 = off[node + 1];
    unsigned long long c0 = 0, c1 = 0;  // byte-packed counts for types 0-7 / 8-15
    for (int i = s0; i < s1; i++) {
        int t = elist[i] & 15;
        if (t < 8) c0 += 1ull << (8 * t); else c1 += 1ull << (8 * (t - 8));
    }
    for (int i = s0; i < s1; i++) {
        int p = elist[i];
        int t = p & 15;
        unsigned int c = (t < 8) ? (unsigned int)((c0 >> (8 * t)) & 255)
                                 : (unsigned int)((c1 >> (8 * (t - 8))) & 255);
        float nrm = 1.0f / (float)max(c, 1u);
        int2 e;
        e.x = p;
        e.y = __float_as_int(nrm);
        epack[i] = e;
    }
}

// ---------------- concept layer: gather-mean from fp16 emb, fp32+fp16 output ----------------
__global__ __launch_bounds__(256) void k_concept_gather(const _Float16* __restrict__ embh,
                                                        const float* __restrict__ emb,
                                                        const int* __restrict__ off,
                                                        const int* __restrict__ elist,
                                                        float* __restrict__ xg1,
                                                        _Float16* __restrict__ xg1h, int n) {
    int node = blockIdx.x * 4 + (threadIdx.x >> 6);
    int lane = threadIdx.x & 63;
    if (node >= n) return;
    int half = lane >> 5, d4 = (lane & 31) * 4;
    int s0 = off[node], s1 = off[node + 1];
    float4 acc = {0.f, 0.f, 0.f, 0.f};
    int i = s0;
    for (; i + 4 <= s1; i += 4) {
        int sa = elist[i + half];
        int sb = elist[i + 2 + half];
        half4 ha = *(const half4*)(embh + (size_t)sa * DIM + d4);
        half4 hb = *(const half4*)(embh + (size_t)sb * DIM + d4);
        acc.x += (float)ha[0] + (float)hb[0];
        acc.y += (float)ha[1] + (float)hb[1];
        acc.z += (float)ha[2] + (float)hb[2];
        acc.w += (float)ha[3] + (float)hb[3];
    }
    for (; i < s1; i += 2) {
        int e = i + half;
        bool ok = e < s1;
        int s = elist[ok ? e : i];
        half4 hv = *(const half4*)(embh + (size_t)s * DIM + d4);
        if (ok) {
            acc.x += (float)hv[0]; acc.y += (float)hv[1];
            acc.z += (float)hv[2]; acc.w += (float)hv[3];
        }
    }
    acc.x += __shfl_xor(acc.x, 32, 64);
    acc.y += __shfl_xor(acc.y, 32, 64);
    acc.z += __shfl_xor(acc.z, 32, 64);
    acc.w += __shfl_xor(acc.w, 32, 64);
    if (half == 0) {
        float inv = 1.0f / (float)max(s1 - s0, 1);
        float4 e = *(const float4*)(emb + (size_t)node * DIM + d4);
        float4 o = {fmaxf(e.x + acc.x * inv, 0.f), fmaxf(e.y + acc.y * inv, 0.f),
                    fmaxf(e.z + acc.z * inv, 0.f), fmaxf(e.w + acc.w * inv, 0.f)};
        *(float4*)(xg1 + (size_t)node * DIM + d4) = o;
        half4 oh = {(_Float16)o.x, (_Float16)o.y, (_Float16)o.z, (_Float16)o.w};
        *(half4*)(xg1h + (size_t)node * DIM + d4) = oh;
    }
}

// ---------------- tyw: concept row lc[l] on the fly -> split bf16 hi/lo, [n][k] layout ----------------
__global__ __launch_bounds__(64) void k_tyw(const float* __restrict__ emb,
                                            const int* __restrict__ off,
                                            const int* __restrict__ elist,
                                            const int* __restrict__ lc,
                                            const float* __restrict__ w,
                                            unsigned short* __restrict__ tyh,
                                            unsigned short* __restrict__ tyl) {
    int l = blockIdx.x;
    int lane = threadIdx.x;
    int d0 = lane * 2;
    if (l >= LCOM) {
        ushort2 z = {0, 0};
        *(ushort2*)(tyh + (size_t)l * 128 + d0) = z;
        *(ushort2*)(tyl + (size_t)l * 128 + d0) = z;
        return;
    }
    int row = lc[l];
    int s0 = off[row], s1 = off[row + 1];
    float2 acc = {0.f, 0.f};
    for (int i = s0; i < s1; i++) {
        int s = elist[i];
        float2 v = *(const float2*)(emb + (size_t)s * DIM + lane * 2);
        acc.x += v.x; acc.y += v.y;
    }
    float inv = 1.0f / (float)max(s1 - s0, 1);
    float2 e = *(const float2*)(emb + (size_t)row * DIM + lane * 2);
    float v0 = fmaxf(e.x + acc.x * inv, 0.f) * w[d0];
    float v1 = fmaxf(e.y + acc.y * inv, 0.f) * w[d0 + 1];
    unsigned short h0 = f2bf(v0), h1 = f2bf(v1);
    ushort2 hh = {h0, h1};
    ushort2 ll = {f2bf(v0 - bf2f(h0)), f2bf(v1 - bf2f(h1))};
    *(ushort2*)(tyh + (size_t)l * 128 + d0) = hh;
    *(ushort2*)(tyl + (size_t)l * 128 + d0) = ll;
}

// ---------------- rgcn aggregation: fp16 gather, packed edge+nrm, LDS comp ----------------
__global__ __launch_bounds__(256) void k_rgcn_gather(const _Float16* __restrict__ xh,
                                                     const int* __restrict__ off,
                                                     const int2* __restrict__ epack,
                                                     const float* __restrict__ comp,
                                                     float* __restrict__ agg, int n) {
    __shared__ float scomp[NREL * NB];
    if (threadIdx.x < NREL * NB) scomp[threadIdx.x] = comp[threadIdx.x];
    __syncthreads();
    int node = blockIdx.x * 4 + (threadIdx.x >> 6);
    int lane = threadIdx.x & 63;
    if (node >= n) return;
    int half = lane >> 5, d4 = (lane & 31) * 4;
    int s0 = off[node], s1 = off[node + 1];
    float4 a0 = {0, 0, 0, 0}, a1 = a0, a2 = a0, a3 = a0;
    int i = s0;
#define RG_EDGE(E_IDX, GATE)                                                   \
    {                                                                          \
        int2 pk = epack[E_IDX];                                                \
        int s = pk.x >> 4, t = pk.x & 15;                                      \
        float nr = __int_as_float(pk.y) * (GATE);                              \
        float4 cf = *(const float4*)(scomp + t * 4);                           \
        half4 hv = *(const half4*)(xh + (size_t)s * DIM + d4);                 \
        float4 v = {(float)hv[0], (float)hv[1], (float)hv[2], (float)hv[3]};   \
        float c0 = cf.x * nr, c1 = cf.y * nr, c2 = cf.z * nr, c3 = cf.w * nr;  \
        a0.x = fmaf(c0, v.x, a0.x); a0.y = fmaf(c0, v.y, a0.y);                \
        a0.z = fmaf(c0, v.z, a0.z); a0.w = fmaf(c0, v.w, a0.w);                \
        a1.x = fmaf(c1, v.x, a1.x); a1.y = fmaf(c1, v.y, a1.y);                \
        a1.z = fmaf(c1, v.z, a1.z); a1.w = fmaf(c1, v.w, a1.w);                \
        a2.x = fmaf(c2, v.x, a2.x); a2.y = fmaf(c2, v.y, a2.y);                \
        a2.z = fmaf(c2, v.z, a2.z); a2.w = fmaf(c2, v.w, a2.w);                \
        a3.x = fmaf(c3, v.x, a3.x); a3.y = fmaf(c3, v.y, a3.y);                \
        a3.z = fmaf(c3, v.z, a3.z); a3.w = fmaf(c3, v.w, a3.w);                \
    }
    for (; i + 4 <= s1; i += 4) {
        RG_EDGE(i + half, 1.0f);
        RG_EDGE(i + 2 + half, 1.0f);
    }
    for (; i < s1; i += 2) {
        int e = i + half;
        bool ok = e < s1;
        int ei_ = ok ? e : i;
        RG_EDGE(ei_, ok ? 1.0f : 0.0f);
    }
#undef RG_EDGE
    a0.x += __shfl_xor(a0.x, 32, 64); a0.y += __shfl_xor(a0.y, 32, 64);
    a0.z += __shfl_xor(a0.z, 32, 64); a0.w += __shfl_xor(a0.w, 32, 64);
    a1.x += __shfl_xor(a1.x, 32, 64); a1.y += __shfl_xor(a1.y, 32, 64);
    a1.z += __shfl_xor(a1.z, 32, 64); a1.w += __shfl_xor(a1.w, 32, 64);
    a2.x += __shfl_xor(a2.x, 32, 64); a2.y += __shfl_xor(a2.y, 32, 64);
    a2.z += __shfl_xor(a2.z, 32, 64); a2.w += __shfl_xor(a2.w, 32, 64);
    a3.x += __shfl_xor(a3.x, 32, 64); a3.y += __shfl_xor(a3.y, 32, 64);
    a3.z += __shfl_xor(a3.z, 32, 64); a3.w += __shfl_xor(a3.w, 32, 64);
    if (half == 0) {
        float* o = agg + (size_t)node * (NB * DIM) + d4;
        *(float4*)(o + 0 * DIM) = a0;
        *(float4*)(o + 1 * DIM) = a1;
        *(float4*)(o + 2 * DIM) = a2;
        *(float4*)(o + 3 * DIM) = a3;
    }
}

// ---------------- split-precision MFMA GEMM (optional fp16 shadow output) ----------------
#define LDSK 40
__global__ __launch_bounds__(256) void k_gemm(const float* __restrict__ x,
                                              const float* __restrict__ agg,
                                              const unsigned short* __restrict__ Wh,
                                              const unsigned short* __restrict__ Wl,
                                              const float* __restrict__ bias,
                                              float* __restrict__ out,
                                              _Float16* __restrict__ out_h, int relu) {
    __shared__ __align__(16) short Ah[128 * LDSK];
    __shared__ __align__(16) short Al[128 * LDSK];
    __shared__ __align__(16) short Bh[128 * LDSK];
    __shared__ __align__(16) short Bl[128 * LDSK];
    int tid = threadIdx.x;
    int lane = tid & 63, wid = tid >> 6;
    int wave_m = wid >> 1, wave_n = wid & 1;
    int l15 = lane & 15, quad = lane >> 4;
    int row0 = blockIdx.x * 128;

    int srow = tid >> 1, skh = (tid & 1) * 16;

    f32x4 acc[4][4] = {};
    for (int k0 = 0; k0 < 640; k0 += 32) {
        {
            int rg = row0 + srow;
            float4 q0 = {0, 0, 0, 0}, q1 = q0, q2 = q0, q3 = q0;
            if (rg < N2) {
                const float* src = (k0 < 128) ? (x + (size_t)rg * 128 + k0 + skh)
                                              : (agg + (size_t)rg * 512 + (k0 - 128) + skh);
                q0 = *(const float4*)(src + 0);
                q1 = *(const float4*)(src + 4);
                q2 = *(const float4*)(src + 8);
                q3 = *(const float4*)(src + 12);
            }
            short8 h0, l0, h1, l1;
            split8(q0, q1, h0, l0);
            split8(q2, q3, h1, l1);
            *(short8*)(&Ah[srow * LDSK + skh]) = h0;
            *(short8*)(&Ah[srow * LDSK + skh + 8]) = h1;
            *(short8*)(&Al[srow * LDSK + skh]) = l0;
            *(short8*)(&Al[srow * LDSK + skh + 8]) = l1;
        }
        {
            const unsigned short* sh = Wh + (size_t)srow * 640 + k0 + skh;
            const unsigned short* sl = Wl + (size_t)srow * 640 + k0 + skh;
            *(short8*)(&Bh[srow * LDSK + skh]) = *(const short8*)(sh);
            *(short8*)(&Bh[srow * LDSK + skh + 8]) = *(const short8*)(sh + 8);
            *(short8*)(&Bl[srow * LDSK + skh]) = *(const short8*)(sl);
            *(short8*)(&Bl[srow * LDSK + skh + 8]) = *(const short8*)(sl + 8);
        }
        __syncthreads();
        short8 ah[4], al[4], bh[4], bl[4];
#pragma unroll
        for (int i = 0; i < 4; i++) {
            int ro = (wave_m * 64 + i * 16 + l15) * LDSK + quad * 8;
            ah[i] = *(const short8*)(&Ah[ro]);
            al[i] = *(const short8*)(&Al[ro]);
        }
#pragma unroll
        for (int j = 0; j < 4; j++) {
            int ro = (wave_n * 64 + j * 16 + l15) * LDSK + quad * 8;
            bh[j] = *(const short8*)(&Bh[ro]);
            bl[j] = *(const short8*)(&Bl[ro]);
        }
#pragma unroll
        for (int i = 0; i < 4; i++)
#pragma unroll
            for (int j = 0; j < 4; j++) {
                acc[i][j] = __builtin_amdgcn_mfma_f32_16x16x32_bf16(al[i], bh[j], acc[i][j], 0, 0, 0);
                acc[i][j] = __builtin_amdgcn_mfma_f32_16x16x32_bf16(ah[i], bl[j], acc[i][j], 0, 0, 0);
                acc[i][j] = __builtin_amdgcn_mfma_f32_16x16x32_bf16(ah[i], bh[j], acc[i][j], 0, 0, 0);
            }
        __syncthreads();
    }
#pragma unroll
    for (int j = 0; j < 4; j++) {
        int gcol = wave_n * 64 + j * 16 + l15;
        float bv = bias[gcol];
#pragma unroll
        for (int i = 0; i < 4; i++) {
            int grow_base = row0 + wave_m * 64 + i * 16 + quad * 4;
#pragma unroll
            for (int r = 0; r < 4; r++) {
                int grow = grow_base + r;
                if (grow >= N2) continue;
                float v = acc[i][j][r] + bv;
                if (relu) v = fmaxf(v, 0.f);
                out[(size_t)grow * 128 + gcol] = v;
                if (out_h) out_h[(size_t)grow * 128 + gcol] = (_Float16)v;
            }
        }
    }
}

// ---------------- logits + softmax: MFMA, no LDS ----------------
__global__ __launch_bounds__(256) void k_logits(const float* __restrict__ h2,
                                                const unsigned short* __restrict__ tyh,
                                                const unsigned short* __restrict__ tyl,
                                                float* __restrict__ out, int M) {
    int wid = threadIdx.x >> 6, lane = threadIdx.x & 63;
    int l15 = lane & 15, quad = lane >> 4;
    int row0w = blockIdx.x * 64 + wid * 16;
    int arow = min(row0w + l15, M - 1);
    f32x4 acc[7] = {};
#pragma unroll
    for (int k0 = 0; k0 < 128; k0 += 32) {
        const float* ap = h2 + (size_t)arow * 128 + k0 + quad * 8;
        float4 q0 = *(const float4*)(ap);
        float4 q1 = *(const float4*)(ap + 4);
        short8 ah, al;
        split8(q0, q1, ah, al);
#pragma unroll
        for (int j = 0; j < 7; j++) {
            size_t bo = (size_t)(j * 16 + l15) * 128 + k0 + quad * 8;
            short8 bh = *(const short8*)(tyh + bo);
            short8 bl = *(const short8*)(tyl + bo);
            acc[j] = __builtin_amdgcn_mfma_f32_16x16x32_bf16(al, bh, acc[j], 0, 0, 0);
            acc[j] = __builtin_amdgcn_mfma_f32_16x16x32_bf16(ah, bl, acc[j], 0, 0, 0);
            acc[j] = __builtin_amdgcn_mfma_f32_16x16x32_bf16(ah, bh, acc[j], 0, 0, 0);
        }
    }
    bool v6 = (l15 < LCOM - 96);
#pragma unroll
    for (int r = 0; r < 4; r++) {
        int grow = row0w + quad * 4 + r;
        float m = -INFINITY;
#pragma unroll
        for (int j = 0; j < 6; j++) m = fmaxf(m, acc[j][r]);
        if (v6) m = fmaxf(m, acc[6][r]);
        m = fmaxf(m, __shfl_xor(m, 8, 64));
        m = fmaxf(m, __shfl_xor(m, 4, 64));
        m = fmaxf(m, __shfl_xor(m, 2, 64));
        m = fmaxf(m, __shfl_xor(m, 1, 64));
        float e[7];
        float s = 0.f;
#pragma unroll
        for (int j = 0; j < 6; j++) { e[j] = __expf(acc[j][r] - m); s += e[j]; }
        e[6] = v6 ? __expf(acc[6][r] - m) : 0.f;
        s += e[6];
        s += __shfl_xor(s, 8, 64);
        s += __shfl_xor(s, 4, 64);
        s += __shfl_xor(s, 2, 64);
        s += __shfl_xor(s, 1, 64);
        float inv = 1.0f / s;
        if (grow < M) {
#pragma unroll
            for (int j = 0; j < 6; j++) out[(size_t)grow * LCOM + j * 16 + l15] = e[j] * inv;
            if (v6) out[(size_t)grow * LCOM + 96 + l15] = e[6] * inv;
        }
    }
}

extern "C" void kernel_launch(void* const* d_in, const int* in_sizes, int n_in,
                              void* d_out, int out_size, void* d_ws, size_t ws_size,
                              hipStream_t stream) {
    const int* ei2 = (const int*)d_in[0];
    const int* et2 = (const int*)d_in[1];
    const int* ei1 = (const int*)d_in[2];
    const int* lc = (const int*)d_in[3];
    const float* emb = (const float*)d_in[4];
    const float* basis1 = (const float*)d_in[5];
    const float* comp1 = (const float*)d_in[6];
    const float* root1 = (const float*)d_in[7];
    const float* bias1 = (const float*)d_in[8];
    const float* basis2 = (const float*)d_in[9];
    const float* comp2 = (const float*)d_in[10];
    const float* root2 = (const float*)d_in[11];
    const float* bias2 = (const float*)d_in[12];
    const float* wts = (const float*)d_in[13];
    float* out = (float*)d_out;
    int E2 = in_sizes[0] / 2, E1 = in_sizes[2] / 2;

    float* ws = (float*)d_ws;
    float* xg1 = ws;                          // 6,400,000 f (reused as h2)
    float* h1 = xg1 + 6400000;                // 6,400,000 f (first half aliased as xg1_h)
    float* agg = h1 + 6400000;                // 25,600,000 f
    _Float16* emb_h = (_Float16*)(agg + 25600000);  // 7,680,000 h (first 6.4M aliased as h1_h)
    int2* epack = (int2*)(emb_h + 7680000);   // 800,000 int2
    unsigned short* tyh = (unsigned short*)(epack + 800000);  // 14,336
    unsigned short* tyl = tyh + LPAD * 128;                   // 14,336
    unsigned short* Wh1 = tyl + LPAD * 128;   // 81,920 each
    unsigned short* Wl1 = Wh1 + 81920;
    unsigned short* Wh2 = Wl1 + 81920;
    unsigned short* Wl2 = Wh2 + 81920;
    int* ipool = (int*)(Wl2 + 81920);
    int* deg1 = ipool;                        // 60,000  (deg1+deg2 adjacent: one memset)
    int* deg2 = deg1 + 60000;                 // 50,000
    int* off1 = deg2 + 50000;                 // 60,001
    int* cur1 = off1 + 60001;                 // 60,000
    int* elist1 = cur1 + 60000;               // 800,000
    int* off2 = elist1 + 800000;              // 50,001
    int* cur2 = off2 + 50001;                 // 50,000
    int* elist2 = cur2 + 50000;               // 800,000
    int* bsum1 = elist2 + 800000;             // 64
    int* boff1 = bsum1 + 64;
    int* bsum2 = boff1 + 64;
    int* boff2 = bsum2 + 64;
    _Float16* xg1_h = (_Float16*)h1;          // alias: h1 written only after gather1 consumed xg1_h
    _Float16* h1_h = emb_h;                   // alias: emb_h consumed by concept before gemm1 writes
    float* h2 = xg1;                          // alias: xg1 dead after gemm1

    const int NB1 = (N1 + 1023) / 1024;       // 59
    const int NB2 = (N2 + 1023) / 1024;       // 49

    // ---- prep: weights, fp16 emb shadow, zero degree arrays ----
    k_prep_w2<<<(2 * 640 * 128 + 255) / 256, 256, 0, stream>>>(root1, basis1, Wh1, Wl1,
                                                               root2, basis2, Wh2, Wl2);
    k_cast_emb<<<(N1 * DIM / 4 + 255) / 256, 256, 0, stream>>>(emb, emb_h, N1 * DIM / 4);
    hipMemsetAsync(deg1, 0, (60000 + 50000) * sizeof(int), stream);

    // ---- CSR build for both graphs ----
    k_hist_both<<<(max(E1, E2) + 255) / 256, 256, 0, stream>>>(ei1, E1, deg1, ei2, E2, deg2);
    k_scan_p1m<<<NB1 + NB2, 256, 0, stream>>>(deg1, N1, NB1, bsum1, deg2, N2, bsum2);
    k_scan_p2m<<<2, 64, 0, stream>>>(bsum1, boff1, off1, NB1, N1, bsum2, boff2, off2, NB2, N2);
    k_scan_p3m<<<NB1 + NB2, 256, 0, stream>>>(deg1, boff1, off1, cur1, N1, NB1,
                                              deg2, boff2, off2, cur2, N2);
    k_scat_both<<<(max(E1, E2) + 255) / 256, 256, 0, stream>>>(ei1, E1, cur1, elist1,
                                                               ei2, et2, E2, cur2, elist2);
    k_nrm_pack<<<(N2 + 255) / 256, 256, 0, stream>>>(off2, elist2, epack, N2);

    // ---- concept layer (rows < 50000) + tyw ----
    k_concept_gather<<<(N2 + 3) / 4, 256, 0, stream>>>(emb_h, emb, off1, elist1, xg1, xg1_h, N2);
    k_tyw<<<LPAD, 64, 0, stream>>>(emb, off1, elist1, lc, wts, tyh, tyl);

    // ---- rgcn layer 1 ----
    k_rgcn_gather<<<(N2 + 3) / 4, 256, 0, stream>>>(xg1_h, off2, epack, comp1, agg, N2);
    k_gemm<<<(N2 + 127) / 128, 256, 0, stream>>>(xg1, agg, Wh1, Wl1, bias1, h1, h1_h, 1);

    // ---- rgcn layer 2 ----
    k_rgcn_gather<<<(N2 + 3) / 4, 256, 0, stream>>>(h1_h, off2, epack, comp2, agg, N2);
    k_gemm<<<(N2 + 127) / 128, 256, 0, stream>>>(h1, agg, Wh2, Wl2, bias2, h2, (_Float16*)nullptr, 0);

    // ---- logits + softmax ----
    k_logits<<<(N2 + 63) / 64, 256, 0, stream>>>(h2, tyh, tyl, out, N2);
}

// Round 11
// 563.478 us; speedup vs baseline: 22.1297x; 1.0602x over previous
//
#include <hip/hip_runtime.h>
#include <hip/hip_bf16.h>
#include <math.h>

#define N1 60000
#define N2 50000
#define DIM 128
#define NREL 16
#define NB 4
#define LCOM 100
#define LPAD 112  // LCOM padded to 7x16 for MFMA N-tiles

typedef __attribute__((ext_vector_type(8))) short short8;
typedef __attribute__((ext_vector_type(4))) float f32x4;
typedef __attribute__((ext_vector_type(4))) _Float16 half4;

__device__ __forceinline__ float bf2f(unsigned short u) {
    union { unsigned int i; float f; } c; c.i = ((unsigned int)u) << 16; return c.f;
}
__device__ __forceinline__ unsigned short f2bf(float f) {
    union { float f; unsigned int i; } c; c.f = f;
    unsigned int r = c.i + 0x7FFF + ((c.i >> 16) & 1);  // RNE
    return (unsigned short)(r >> 16);
}
__device__ __forceinline__ void split8(float4 a, float4 b, short8& h, short8& l) {
    float f[8] = {a.x, a.y, a.z, a.w, b.x, b.y, b.z, b.w};
#pragma unroll
    for (int j = 0; j < 8; j++) {
        unsigned short hh = f2bf(f[j]);
        h[j] = (short)hh;
        l[j] = (short)f2bf(f[j] - bf2f(hh));
    }
}

// ---------------- prelude: hist1 ∪ hist2 ∪ weight prep ∪ emb cast (independent block ranges) ----------------
__global__ __launch_bounds__(256) void k_prelude(
        const int* __restrict__ ei1, int E1, int* __restrict__ deg1, int HB1,
        const int* __restrict__ ei2, int E2, int* __restrict__ deg2, int HB2,
        const float* __restrict__ root1, const float* __restrict__ basis1,
        unsigned short* __restrict__ Wh1, unsigned short* __restrict__ Wl1,
        const float* __restrict__ root2, const float* __restrict__ basis2,
        unsigned short* __restrict__ Wh2, unsigned short* __restrict__ Wl2, int PB,
        const float* __restrict__ emb, _Float16* __restrict__ embh, int n4) {
    int b = blockIdx.x;
    if (b < HB1) {
        int e0 = b * 1024 + threadIdx.x;
#pragma unroll
        for (int j = 0; j < 4; j++) {
            int e = e0 + j * 256;
            if (e < E1) atomicAdd(deg1 + ei1[E1 + e], 1);
        }
    } else if (b < HB1 + HB2) {
        int e0 = (b - HB1) * 1024 + threadIdx.x;
#pragma unroll
        for (int j = 0; j < 4; j++) {
            int e = e0 + j * 256;
            if (e < E2) atomicAdd(deg2 + ei2[E2 + e], 1);
        }
    } else if (b < HB1 + HB2 + PB) {
        int t = (b - HB1 - HB2) * 256 + threadIdx.x;
        if (t < 2 * 640 * 128) {
            int which = t >= 640 * 128;
            int tt = which ? t - 640 * 128 : t;
            const float* root = which ? root2 : root1;
            const float* basis = which ? basis2 : basis1;
            unsigned short* Wh = which ? Wh2 : Wh1;
            unsigned short* Wl = which ? Wl2 : Wl1;
            int k = tt >> 7, n = tt & 127;
            float v = (k < 128) ? root[k * 128 + n] : basis[(k - 128) * 128 + n];
            unsigned short h = f2bf(v);
            Wh[n * 640 + k] = h;
            Wl[n * 640 + k] = f2bf(v - bf2f(h));
        }
    } else {
        int i = (b - HB1 - HB2 - PB) * 256 + threadIdx.x;
        if (i < n4) {
            float4 v = ((const float4*)emb)[i];
            half4 o = {(_Float16)v.x, (_Float16)v.y, (_Float16)v.z, (_Float16)v.w};
            ((half4*)embh)[i] = o;
        }
    }
}

// ---------------- merged hierarchical scan (two arrays per phase) ----------------
__global__ __launch_bounds__(256) void k_scan_p1m(const int* __restrict__ inA, int nA, int nbA,
                                                  int* __restrict__ bsumA,
                                                  const int* __restrict__ inB, int nB,
                                                  int* __restrict__ bsumB) {
    __shared__ int red[256];
    const int* in; int n; int* bsum; int b;
    if ((int)blockIdx.x < nbA) { in = inA; n = nA; bsum = bsumA; b = blockIdx.x; }
    else { in = inB; n = nB; bsum = bsumB; b = blockIdx.x - nbA; }
    int base = b * 1024;
    int tid = threadIdx.x;
    int s = 0;
#pragma unroll
    for (int j = 0; j < 4; j++) {
        int i = base + tid * 4 + j;
        if (i < n) s += in[i];
    }
    red[tid] = s;
    __syncthreads();
    for (int d = 128; d; d >>= 1) {
        if (tid < d) red[tid] += red[tid + d];
        __syncthreads();
    }
    if (tid == 0) bsum[b] = red[0];
}

__global__ __launch_bounds__(64) void k_scan_p2m(const int* __restrict__ bsumA, int* __restrict__ boffA,
                                                 int* __restrict__ offA, int nbA, int nA,
                                                 const int* __restrict__ bsumB, int* __restrict__ boffB,
                                                 int* __restrict__ offB, int nbB, int nB) {
    __shared__ int s[64];
    const int* bsum; int* boff; int* off; int nb; int n;
    if (blockIdx.x == 0) { bsum = bsumA; boff = boffA; off = offA; nb = nbA; n = nA; }
    else { bsum = bsumB; boff = boffB; off = offB; nb = nbB; n = nB; }
    int tid = threadIdx.x;
    int v = (tid < nb) ? bsum[tid] : 0;
    s[tid] = v;
    __syncthreads();
    for (int d = 1; d < 64; d <<= 1) {
        int t = (tid >= d) ? s[tid - d] : 0;
        __syncthreads();
        s[tid] += t;
        __syncthreads();
    }
    if (tid < nb) boff[tid] = s[tid] - v;
    if (tid == 63) off[n] = s[63];
}

__global__ __launch_bounds__(256) void k_scan_p3m(const int* __restrict__ inA, const int* __restrict__ boffA,
                                                  int* __restrict__ offA, int* __restrict__ curA,
                                                  int nA, int nbA,
                                                  const int* __restrict__ inB, const int* __restrict__ boffB,
                                                  int* __restrict__ offB, int* __restrict__ curB, int nB) {
    __shared__ int red[256];
    const int* in; const int* boff; int* off; int* cur; int n; int b;
    if ((int)blockIdx.x < nbA) { in = inA; boff = boffA; off = offA; cur = curA; n = nA; b = blockIdx.x; }
    else { in = inB; boff = boffB; off = offB; cur = curB; n = nB; b = blockIdx.x - nbA; }
    int base = b * 1024;
    int tid = threadIdx.x;
    int v[4];
    int s = 0;
#pragma unroll
    for (int j = 0; j < 4; j++) {
        int i = base + tid * 4 + j;
        v[j] = (i < n) ? in[i] : 0;
        s += v[j];
    }
    red[tid] = s;
    __syncthreads();
    for (int d = 1; d < 256; d <<= 1) {
        int t = (tid >= d) ? red[tid - d] : 0;
        __syncthreads();
        red[tid] += t;
        __syncthreads();
    }
    int run = boff[b] + red[tid] - s;
#pragma unroll
    for (int j = 0; j < 4; j++) {
        int i = base + tid * 4 + j;
        if (i < n) {
            off[i] = run; cur[i] = run;
            run += v[j];
        }
    }
}

// ---------------- g1 CSR scatter (4 edges/thread, coalesced) ----------------
__global__ void k_scat1(const int* __restrict__ ei, int E, int* __restrict__ cur,
                        int* __restrict__ elist) {
    int e0 = blockIdx.x * 1024 + threadIdx.x;
#pragma unroll
    for (int j = 0; j < 4; j++) {
        int e = e0 + j * 256;
        if (e < E) {
            int pos = atomicAdd(cur + ei[E + e], 1);
            elist[pos] = ei[e];
        }
    }
}

// ---------------- mix: concept_gather ∪ scat2 ∪ tyw (independent block ranges) ----------------
__global__ __launch_bounds__(256) void k_mix(
        const _Float16* __restrict__ embh, const float* __restrict__ emb,
        const int* __restrict__ off1, const int* __restrict__ elist1,
        float* __restrict__ xg1, _Float16* __restrict__ xg1h, int CONC_B,
        const int* __restrict__ ei2, const int* __restrict__ et2, int E2,
        int* __restrict__ cur2, int* __restrict__ elist2, int SC2_B,
        const int* __restrict__ lc, const float* __restrict__ w,
        unsigned short* __restrict__ tyh, unsigned short* __restrict__ tyl) {
    int b = blockIdx.x;
    if (b < CONC_B) {
        // ---- concept gather-mean (fp16 in, fp32+fp16 out) ----
        int node = b * 4 + (threadIdx.x >> 6);
        int lane = threadIdx.x & 63;
        if (node >= N2) return;
        int half = lane >> 5, d4 = (lane & 31) * 4;
        int s0 = off1[node], s1 = off1[node + 1];
        float4 acc = {0.f, 0.f, 0.f, 0.f};
        int i = s0;
        for (; i + 4 <= s1; i += 4) {
            int sa = elist1[i + half];
            int sb = elist1[i + 2 + half];
            half4 ha = *(const half4*)(embh + (size_t)sa * DIM + d4);
            half4 hb = *(const half4*)(embh + (size_t)sb * DIM + d4);
            acc.x += (float)ha[0] + (float)hb[0];
            acc.y += (float)ha[1] + (float)hb[1];
            acc.z += (float)ha[2] + (float)hb[2];
            acc.w += (float)ha[3] + (float)hb[3];
        }
        for (; i < s1; i += 2) {
            int e = i + half;
            bool ok = e < s1;
            int s = elist1[ok ? e : i];
            half4 hv = *(const half4*)(embh + (size_t)s * DIM + d4);
            if (ok) {
                acc.x += (float)hv[0]; acc.y += (float)hv[1];
                acc.z += (float)hv[2]; acc.w += (float)hv[3];
            }
        }
        acc.x += __shfl_xor(acc.x, 32, 64);
        acc.y += __shfl_xor(acc.y, 32, 64);
        acc.z += __shfl_xor(acc.z, 32, 64);
        acc.w += __shfl_xor(acc.w, 32, 64);
        if (half == 0) {
            float inv = 1.0f / (float)max(s1 - s0, 1);
            float4 e = *(const float4*)(emb + (size_t)node * DIM + d4);
            float4 o = {fmaxf(e.x + acc.x * inv, 0.f), fmaxf(e.y + acc.y * inv, 0.f),
                        fmaxf(e.z + acc.z * inv, 0.f), fmaxf(e.w + acc.w * inv, 0.f)};
            *(float4*)(xg1 + (size_t)node * DIM + d4) = o;
            half4 oh = {(_Float16)o.x, (_Float16)o.y, (_Float16)o.z, (_Float16)o.w};
            *(half4*)(xg1h + (size_t)node * DIM + d4) = oh;
        }
    } else if (b < CONC_B + SC2_B) {
        // ---- g2 CSR scatter (4 edges/thread) ----
        int e0 = (b - CONC_B) * 1024 + threadIdx.x;
#pragma unroll
        for (int j = 0; j < 4; j++) {
            int e = e0 + j * 256;
            if (e < E2) {
                int pos = atomicAdd(cur2 + ei2[E2 + e], 1);
                elist2[pos] = (ei2[e] << 4) | et2[e];
            }
        }
    } else {
        // ---- tyw: concept row lc[l] -> split bf16 hi/lo ----
        if (threadIdx.x >= 64) return;
        int l = b - CONC_B - SC2_B;
        int lane = threadIdx.x;
        int d0 = lane * 2;
        if (l >= LCOM) {
            ushort2 z = {0, 0};
            *(ushort2*)(tyh + (size_t)l * 128 + d0) = z;
            *(ushort2*)(tyl + (size_t)l * 128 + d0) = z;
            return;
        }
        int row = lc[l];
        int s0 = off1[row], s1 = off1[row + 1];
        float2 acc = {0.f, 0.f};
        for (int i = s0; i < s1; i++) {
            int s = elist1[i];
            float2 v = *(const float2*)(emb + (size_t)s * DIM + lane * 2);
            acc.x += v.x; acc.y += v.y;
        }
        float inv = 1.0f / (float)max(s1 - s0, 1);
        float2 e = *(const float2*)(emb + (size_t)row * DIM + lane * 2);
        float v0 = fmaxf(e.x + acc.x * inv, 0.f) * w[d0];
        float v1 = fmaxf(e.y + acc.y * inv, 0.f) * w[d0 + 1];
        unsigned short h0 = f2bf(v0), h1 = f2bf(v1);
        ushort2 hh = {h0, h1};
        ushort2 ll = {f2bf(v0 - bf2f(h0)), f2bf(v1 - bf2f(h1))};
        *(ushort2*)(tyh + (size_t)l * 128 + d0) = hh;
        *(ushort2*)(tyl + (size_t)l * 128 + d0) = ll;
    }
}

// ---------------- rgcn aggregation: fp16 gather, inline per-node type counts ----------------
__global__ __launch_bounds__(256) void k_rgcn_gather(const _Float16* __restrict__ xh,
                                                     const int* __restrict__ off,
                                                     const int* __restrict__ elist,
                                                     const float* __restrict__ comp,
                                                     float* __restrict__ agg, int n) {
    __shared__ float scomp[NREL * NB];
    __shared__ float nrmlds[4][NREL];
    if (threadIdx.x < NREL * NB) scomp[threadIdx.x] = comp[threadIdx.x];
    __syncthreads();
    int nb = threadIdx.x >> 6;
    int node = blockIdx.x * 4 + nb;
    int lane = threadIdx.x & 63;
    if (node >= n) return;
    int s0 = off[node], s1 = off[node + 1];
    // prescan: byte-packed per-type counts, lane-parallel then shfl-reduce
    unsigned long long c0 = 0, c1 = 0;
    for (int i = s0 + lane; i < s1; i += 64) {
        int t = elist[i] & 15;
        if (t < 8) c0 += 1ull << (8 * t); else c1 += 1ull << (8 * (t - 8));
    }
#pragma unroll
    for (int o = 32; o; o >>= 1) {
        c0 += __shfl_xor(c0, o, 64);
        c1 += __shfl_xor(c1, o, 64);
    }
    if (lane < NREL) {
        unsigned int c = (lane < 8) ? (unsigned int)((c0 >> (8 * lane)) & 255)
                                    : (unsigned int)((c1 >> (8 * (lane - 8))) & 255);
        nrmlds[nb][lane] = 1.0f / (float)max(c, 1u);
    }
    // same-wave LDS write->read: no barrier needed
    int half = lane >> 5, d4 = (lane & 31) * 4;
    float4 a0 = {0, 0, 0, 0}, a1 = a0, a2 = a0, a3 = a0;
    int i = s0;
#define RG_EDGE(E_IDX, GATE)                                                   \
    {                                                                          \
        int p = elist[E_IDX];                                                  \
        int s = p >> 4, t = p & 15;                                            \
        float nr = nrmlds[nb][t] * (GATE);                                     \
        float4 cf = *(const float4*)(scomp + t * 4);                           \
        half4 hv = *(const half4*)(xh + (size_t)s * DIM + d4);                 \
        float4 v = {(float)hv[0], (float)hv[1], (float)hv[2], (float)hv[3]};   \
        float c0_ = cf.x * nr, c1_ = cf.y * nr, c2_ = cf.z * nr, c3_ = cf.w * nr; \
        a0.x = fmaf(c0_, v.x, a0.x); a0.y = fmaf(c0_, v.y, a0.y);              \
        a0.z = fmaf(c0_, v.z, a0.z); a0.w = fmaf(c0_, v.w, a0.w);              \
        a1.x = fmaf(c1_, v.x, a1.x); a1.y = fmaf(c1_, v.y, a1.y);              \
        a1.z = fmaf(c1_, v.z, a1.z); a1.w = fmaf(c1_, v.w, a1.w);              \
        a2.x = fmaf(c2_, v.x, a2.x); a2.y = fmaf(c2_, v.y, a2.y);              \
        a2.z = fmaf(c2_, v.z, a2.z); a2.w = fmaf(c2_, v.w, a2.w);              \
        a3.x = fmaf(c3_, v.x, a3.x); a3.y = fmaf(c3_, v.y, a3.y);              \
        a3.z = fmaf(c3_, v.z, a3.z); a3.w = fmaf(c3_, v.w, a3.w);              \
    }
    for (; i + 4 <= s1; i += 4) {
        RG_EDGE(i + half, 1.0f);
        RG_EDGE(i + 2 + half, 1.0f);
    }
    for (; i < s1; i += 2) {
        int e = i + half;
        bool ok = e < s1;
        int ei_ = ok ? e : i;
        RG_EDGE(ei_, ok ? 1.0f : 0.0f);
    }
#undef RG_EDGE
    a0.x += __shfl_xor(a0.x, 32, 64); a0.y += __shfl_xor(a0.y, 32, 64);
    a0.z += __shfl_xor(a0.z, 32, 64); a0.w += __shfl_xor(a0.w, 32, 64);
    a1.x += __shfl_xor(a1.x, 32, 64); a1.y += __shfl_xor(a1.y, 32, 64);
    a1.z += __shfl_xor(a1.z, 32, 64); a1.w += __shfl_xor(a1.w, 32, 64);
    a2.x += __shfl_xor(a2.x, 32, 64); a2.y += __shfl_xor(a2.y, 32, 64);
    a2.z += __shfl_xor(a2.z, 32, 64); a2.w += __shfl_xor(a2.w, 32, 64);
    a3.x += __shfl_xor(a3.x, 32, 64); a3.y += __shfl_xor(a3.y, 32, 64);
    a3.z += __shfl_xor(a3.z, 32, 64); a3.w += __shfl_xor(a3.w, 32, 64);
    if (half == 0) {
        float* o = agg + (size_t)node * (NB * DIM) + d4;
        *(float4*)(o + 0 * DIM) = a0;
        *(float4*)(o + 1 * DIM) = a1;
        *(float4*)(o + 2 * DIM) = a2;
        *(float4*)(o + 3 * DIM) = a3;
    }
}

// ---------------- split-precision MFMA GEMM (optional fp16 shadow output) ----------------
#define LDSK 40
__global__ __launch_bounds__(256) void k_gemm(const float* __restrict__ x,
                                              const float* __restrict__ agg,
                                              const unsigned short* __restrict__ Wh,
                                              const unsigned short* __restrict__ Wl,
                                              const float* __restrict__ bias,
                                              float* __restrict__ out,
                                              _Float16* __restrict__ out_h, int relu) {
    __shared__ __align__(16) short Ah[128 * LDSK];
    __shared__ __align__(16) short Al[128 * LDSK];
    __shared__ __align__(16) short Bh[128 * LDSK];
    __shared__ __align__(16) short Bl[128 * LDSK];
    int tid = threadIdx.x;
    int lane = tid & 63, wid = tid >> 6;
    int wave_m = wid >> 1, wave_n = wid & 1;
    int l15 = lane & 15, quad = lane >> 4;
    int row0 = blockIdx.x * 128;

    int srow = tid >> 1, skh = (tid & 1) * 16;

    f32x4 acc[4][4] = {};
    for (int k0 = 0; k0 < 640; k0 += 32) {
        {
            int rg = row0 + srow;
            float4 q0 = {0, 0, 0, 0}, q1 = q0, q2 = q0, q3 = q0;
            if (rg < N2) {
                const float* src = (k0 < 128) ? (x + (size_t)rg * 128 + k0 + skh)
                                              : (agg + (size_t)rg * 512 + (k0 - 128) + skh);
                q0 = *(const float4*)(src + 0);
                q1 = *(const float4*)(src + 4);
                q2 = *(const float4*)(src + 8);
                q3 = *(const float4*)(src + 12);
            }
            short8 h0, l0, h1, l1;
            split8(q0, q1, h0, l0);
            split8(q2, q3, h1, l1);
            *(short8*)(&Ah[srow * LDSK + skh]) = h0;
            *(short8*)(&Ah[srow * LDSK + skh + 8]) = h1;
            *(short8*)(&Al[srow * LDSK + skh]) = l0;
            *(short8*)(&Al[srow * LDSK + skh + 8]) = l1;
        }
        {
            const unsigned short* sh = Wh + (size_t)srow * 640 + k0 + skh;
            const unsigned short* sl = Wl + (size_t)srow * 640 + k0 + skh;
            *(short8*)(&Bh[srow * LDSK + skh]) = *(const short8*)(sh);
            *(short8*)(&Bh[srow * LDSK + skh + 8]) = *(const short8*)(sh + 8);
            *(short8*)(&Bl[srow * LDSK + skh]) = *(const short8*)(sl);
            *(short8*)(&Bl[srow * LDSK + skh + 8]) = *(const short8*)(sl + 8);
        }
        __syncthreads();
        short8 ah[4], al[4], bh[4], bl[4];
#pragma unroll
        for (int i = 0; i < 4; i++) {
            int ro = (wave_m * 64 + i * 16 + l15) * LDSK + quad * 8;
            ah[i] = *(const short8*)(&Ah[ro]);
            al[i] = *(const short8*)(&Al[ro]);
        }
#pragma unroll
        for (int j = 0; j < 4; j++) {
            int ro = (wave_n * 64 + j * 16 + l15) * LDSK + quad * 8;
            bh[j] = *(const short8*)(&Bh[ro]);
            bl[j] = *(const short8*)(&Bl[ro]);
        }
#pragma unroll
        for (int i = 0; i < 4; i++)
#pragma unroll
            for (int j = 0; j < 4; j++) {
                acc[i][j] = __builtin_amdgcn_mfma_f32_16x16x32_bf16(al[i], bh[j], acc[i][j], 0, 0, 0);
                acc[i][j] = __builtin_amdgcn_mfma_f32_16x16x32_bf16(ah[i], bl[j], acc[i][j], 0, 0, 0);
                acc[i][j] = __builtin_amdgcn_mfma_f32_16x16x32_bf16(ah[i], bh[j], acc[i][j], 0, 0, 0);
            }
        __syncthreads();
    }
#pragma unroll
    for (int j = 0; j < 4; j++) {
        int gcol = wave_n * 64 + j * 16 + l15;
        float bv = bias[gcol];
#pragma unroll
        for (int i = 0; i < 4; i++) {
            int grow_base = row0 + wave_m * 64 + i * 16 + quad * 4;
#pragma unroll
            for (int r = 0; r < 4; r++) {
                int grow = grow_base + r;
                if (grow >= N2) continue;
                float v = acc[i][j][r] + bv;
                if (relu) v = fmaxf(v, 0.f);
                out[(size_t)grow * 128 + gcol] = v;
                if (out_h) out_h[(size_t)grow * 128 + gcol] = (_Float16)v;
            }
        }
    }
}

// ---------------- logits + softmax: MFMA, no LDS ----------------
__global__ __launch_bounds__(256) void k_logits(const float* __restrict__ h2,
                                                const unsigned short* __restrict__ tyh,
                                                const unsigned short* __restrict__ tyl,
                                                float* __restrict__ out, int M) {
    int wid = threadIdx.x >> 6, lane = threadIdx.x & 63;
    int l15 = lane & 15, quad = lane >> 4;
    int row0w = blockIdx.x * 64 + wid * 16;
    int arow = min(row0w + l15, M - 1);
    f32x4 acc[7] = {};
#pragma unroll
    for (int k0 = 0; k0 < 128; k0 += 32) {
        const float* ap = h2 + (size_t)arow * 128 + k0 + quad * 8;
        float4 q0 = *(const float4*)(ap);
        float4 q1 = *(const float4*)(ap + 4);
        short8 ah, al;
        split8(q0, q1, ah, al);
#pragma unroll
        for (int j = 0; j < 7; j++) {
            size_t bo = (size_t)(j * 16 + l15) * 128 + k0 + quad * 8;
            short8 bh = *(const short8*)(tyh + bo);
            short8 bl = *(const short8*)(tyl + bo);
            acc[j] = __builtin_amdgcn_mfma_f32_16x16x32_bf16(al, bh, acc[j], 0, 0, 0);
            acc[j] = __builtin_amdgcn_mfma_f32_16x16x32_bf16(ah, bl, acc[j], 0, 0, 0);
            acc[j] = __builtin_amdgcn_mfma_f32_16x16x32_bf16(ah, bh, acc[j], 0, 0, 0);
        }
    }
    bool v6 = (l15 < LCOM - 96);
#pragma unroll
    for (int r = 0; r < 4; r++) {
        int grow = row0w + quad * 4 + r;
        float m = -INFINITY;
#pragma unroll
        for (int j = 0; j < 6; j++) m = fmaxf(m, acc[j][r]);
        if (v6) m = fmaxf(m, acc[6][r]);
        m = fmaxf(m, __shfl_xor(m, 8, 64));
        m = fmaxf(m, __shfl_xor(m, 4, 64));
        m = fmaxf(m, __shfl_xor(m, 2, 64));
        m = fmaxf(m, __shfl_xor(m, 1, 64));
        float e[7];
        float s = 0.f;
#pragma unroll
        for (int j = 0; j < 6; j++) { e[j] = __expf(acc[j][r] - m); s += e[j]; }
        e[6] = v6 ? __expf(acc[6][r] - m) : 0.f;
        s += e[6];
        s += __shfl_xor(s, 8, 64);
        s += __shfl_xor(s, 4, 64);
        s += __shfl_xor(s, 2, 64);
        s += __shfl_xor(s, 1, 64);
        float inv = 1.0f / s;
        if (grow < M) {
#pragma unroll
            for (int j = 0; j < 6; j++) out[(size_t)grow * LCOM + j * 16 + l15] = e[j] * inv;
            if (v6) out[(size_t)grow * LCOM + 96 + l15] = e[6] * inv;
        }
    }
}

extern "C" void kernel_launch(void* const* d_in, const int* in_sizes, int n_in,
                              void* d_out, int out_size, void* d_ws, size_t ws_size,
                              hipStream_t stream) {
    const int* ei2 = (const int*)d_in[0];
    const int* et2 = (const int*)d_in[1];
    const int* ei1 = (const int*)d_in[2];
    const int* lc = (const int*)d_in[3];
    const float* emb = (const float*)d_in[4];
    const float* basis1 = (const float*)d_in[5];
    const float* comp1 = (const float*)d_in[6];
    const float* root1 = (const float*)d_in[7];
    const float* bias1 = (const float*)d_in[8];
    const float* basis2 = (const float*)d_in[9];
    const float* comp2 = (const float*)d_in[10];
    const float* root2 = (const float*)d_in[11];
    const float* bias2 = (const float*)d_in[12];
    const float* wts = (const float*)d_in[13];
    float* out = (float*)d_out;
    int E2 = in_sizes[0] / 2, E1 = in_sizes[2] / 2;

    float* ws = (float*)d_ws;
    float* xg1 = ws;                          // 6,400,000 f (reused as h2)
    float* h1 = xg1 + 6400000;                // 6,400,000 f (first half aliased as xg1_h)
    float* agg = h1 + 6400000;                // 25,600,000 f
    _Float16* emb_h = (_Float16*)(agg + 25600000);  // 7,680,000 h (first 6.4M aliased as h1_h)
    unsigned short* tyh = (unsigned short*)(emb_h + 7680000);  // 14,336
    unsigned short* tyl = tyh + LPAD * 128;                    // 14,336
    unsigned short* Wh1 = tyl + LPAD * 128;   // 81,920 each
    unsigned short* Wl1 = Wh1 + 81920;
    unsigned short* Wh2 = Wl1 + 81920;
    unsigned short* Wl2 = Wh2 + 81920;
    int* ipool = (int*)(Wl2 + 81920);
    int* deg1 = ipool;                        // 60,000 (deg1+deg2 adjacent: one memset)
    int* deg2 = deg1 + 60000;                 // 50,000
    int* off1 = deg2 + 50000;                 // 60,001
    int* cur1 = off1 + 60001;                 // 60,000
    int* elist1 = cur1 + 60000;               // 800,000
    int* off2 = elist1 + 800000;              // 50,001
    int* cur2 = off2 + 50001;                 // 50,000
    int* elist2 = cur2 + 50000;               // 800,000
    int* bsum1 = elist2 + 800000;             // 64
    int* boff1 = bsum1 + 64;
    int* bsum2 = boff1 + 64;
    int* boff2 = bsum2 + 64;
    _Float16* xg1_h = (_Float16*)h1;          // alias: gather1 consumes xg1_h before gemm1 writes h1
    _Float16* h1_h = emb_h;                   // alias: emb_h consumed by k_mix before gemm1 writes
    float* h2 = xg1;                          // alias: xg1 dead after gemm1

    const int NB1 = (N1 + 1023) / 1024;       // 59
    const int NB2 = (N2 + 1023) / 1024;       // 49
    const int HB1 = (E1 + 1023) / 1024;
    const int HB2 = (E2 + 1023) / 1024;
    const int PB = (2 * 640 * 128) / 256;     // 640
    const int CB = (N1 * DIM / 4 + 255) / 256;  // 7500
    const int CONC_B = (N2 + 3) / 4;          // 12500
    const int SC2_B = HB2;

    // 1) zero degree arrays
    hipMemsetAsync(deg1, 0, (60000 + 50000) * sizeof(int), stream);

    // 2) prelude: hist1 ∪ hist2 ∪ weight prep ∪ emb cast
    k_prelude<<<HB1 + HB2 + PB + CB, 256, 0, stream>>>(
        ei1, E1, deg1, HB1, ei2, E2, deg2, HB2,
        root1, basis1, Wh1, Wl1, root2, basis2, Wh2, Wl2, PB,
        emb, emb_h, N1 * DIM / 4);

    // 3-5) merged scans for both CSRs
    k_scan_p1m<<<NB1 + NB2, 256, 0, stream>>>(deg1, N1, NB1, bsum1, deg2, N2, bsum2);
    k_scan_p2m<<<2, 64, 0, stream>>>(bsum1, boff1, off1, NB1, N1, bsum2, boff2, off2, NB2, N2);
    k_scan_p3m<<<NB1 + NB2, 256, 0, stream>>>(deg1, boff1, off1, cur1, N1, NB1,
                                              deg2, boff2, off2, cur2, N2);

    // 6) g1 scatter (exposed)
    k_scat1<<<HB1, 256, 0, stream>>>(ei1, E1, cur1, elist1);

    // 7) mix: concept ∪ g2 scatter ∪ tyw
    k_mix<<<CONC_B + SC2_B + LPAD, 256, 0, stream>>>(
        emb_h, emb, off1, elist1, xg1, xg1_h, CONC_B,
        ei2, et2, E2, cur2, elist2, SC2_B,
        lc, wts, tyh, tyl);

    // 8-9) rgcn layer 1
    k_rgcn_gather<<<CONC_B, 256, 0, stream>>>(xg1_h, off2, elist2, comp1, agg, N2);
    k_gemm<<<(N2 + 127) / 128, 256, 0, stream>>>(xg1, agg, Wh1, Wl1, bias1, h1, h1_h, 1);

    // 10-11) rgcn layer 2
    k_rgcn_gather<<<CONC_B, 256, 0, stream>>>(h1_h, off2, elist2, comp2, agg, N2);
    k_gemm<<<(N2 + 127) / 128, 256, 0, stream>>>(h1, agg, Wh2, Wl2, bias2, h2, (_Float16*)nullptr, 0);

    // 12) logits + softmax
    k_logits<<<(N2 + 63) / 64, 256, 0, stream>>>(h2, tyh, tyl, out, N2);
}